// Round 13
// baseline (2705.607 us; speedup 1.0000x reference)
//
#include <hip/hip_runtime.h>

#define DD 800
#define HH 800
#define BB 64
#define TT 48
#define N3H 2400
#define VV 32000
#define MR (TT*BB)   // 3072 rows, time-major (t*BB + b)
#define NBLK 25      // scan workers: 25 x 32 H-columns; blocks >= NBLK are GEMM helpers

typedef __attribute__((ext_vector_type(8))) short bf16x8;
typedef __attribute__((ext_vector_type(4))) float f32x4;
typedef __attribute__((ext_vector_type(4))) float float4v;
typedef __attribute__((ext_vector_type(4))) int int4v;
typedef __attribute__((address_space(1))) const unsigned int as1_uint;
typedef __attribute__((address_space(3))) unsigned int as3_uint;

__device__ __forceinline__ short f2bf(float f) {
  unsigned int u = __builtin_bit_cast(unsigned int, f);
  u = (u + 0x7fffu + ((u >> 16) & 1u)) >> 16;
  return (short)(unsigned short)u;
}

__device__ __forceinline__ void gload16(const void* g, void* l) {
  __builtin_amdgcn_global_load_lds((as1_uint*)g, (as3_uint*)l, 16, 0, 0);
}

// device-coherent 16B store: write-through to IC (visible chip-wide after vmcnt drain).
__device__ __forceinline__ void store16_cc(short* p, bf16x8 v) {
  asm volatile("global_store_dwordx4 %0, %1, off sc0 sc1" :: "v"(p), "v"(v));
}
// device-coherent 16B load, no wait (caller batches + s_waitcnt + sched_barrier).
__device__ __forceinline__ bf16x8 load16_cc_nw(const short* p) {
  bf16x8 v;
  asm volatile("global_load_dwordx4 %0, %1, off sc0 sc1" : "=&v"(v) : "v"(p));
  return v;
}

// ---------------- transpose + cast fp32 [K][N] -> bf16 [N][K] ----------------
__global__ void k_cast_transpose(const float* __restrict__ src, short* __restrict__ dst,
                                 int K, int N) {
  __shared__ float tile[32][33];
  int n0 = blockIdx.x * 32, k0 = blockIdx.y * 32;
  int tx = threadIdx.x, ty = threadIdx.y;   // (32,8)
#pragma unroll
  for (int i = 0; i < 4; ++i) {
    int k = k0 + ty + i * 8, n = n0 + tx;
    if (k < K && n < N) tile[ty + i * 8][tx] = src[(size_t)k * N + n];
  }
  __syncthreads();
#pragma unroll
  for (int i = 0; i < 4; ++i) {
    int n = n0 + ty + i * 8, k = k0 + tx;
    if (n < N && k < K) dst[(size_t)n * K + k] = f2bf(tile[tx][ty + i * 8]);
  }
}

// ---------------- gather embedding rows -> bf16, time-major ----------------
__global__ void k_gather(const int* __restrict__ ids, const float* __restrict__ emb,
                         short* __restrict__ out) {
  int r = blockIdx.x;            // r = t*BB + b
  int t = r >> 6, b = r & 63;
  int id = ids[b * TT + t];
  int i = threadIdx.x;
  if (i < 100) {
    const float* s = emb + (size_t)id * DD + i * 8;
    float4v v0 = *(const float4v*)s;
    float4v v1 = *(const float4v*)(s + 4);
    bf16x8 o;
    o[0] = f2bf(v0[0]); o[1] = f2bf(v0[1]); o[2] = f2bf(v0[2]); o[3] = f2bf(v0[3]);
    o[4] = f2bf(v1[0]); o[5] = f2bf(v1[1]); o[6] = f2bf(v1[2]); o[7] = f2bf(v1[3]);
    *(bf16x8*)(out + (size_t)r * DD + i * 8) = o;
  }
}

// ---------------- standalone bf16 GEMM (prologue only) ----------------
// EPI 0: fp32 store + bias (xg).  EPI 1: relu -> bf16 (fe).
template <int EPI>
__global__ __launch_bounds__(256) void k_gemm(const short* __restrict__ A,
                                              const short* __restrict__ BT,
                                              const float* __restrict__ bias,
                                              float* __restrict__ Cf,
                                              short* __restrict__ Cb,
                                              int N, int K, int ldc) {
  __shared__ short lA[128 * 32];
  __shared__ short lB[128 * 32];
  const int tid = threadIdx.x, wid = tid >> 6, lane = tid & 63;
  const int m0 = blockIdx.y * 128, n0 = blockIdx.x * 128;
  const int wr = wid >> 1, wc = wid & 1;
  f32x4 acc[4][4] = {};
  for (int kt = 0; kt < K / 32; ++kt) {
    const int kb = kt * 32;
#pragma unroll
    for (int rr = 0; rr < 2; ++rr) {
      int s = rr * 256 + tid;
      gload16(A + (size_t)(m0 + (s >> 2)) * K + kb + (s & 3) * 8, (char*)lA + s * 16);
      gload16(BT + (size_t)(n0 + (s >> 2)) * K + kb + (s & 3) * 8, (char*)lB + s * 16);
    }
    __syncthreads();
    bf16x8 af[4], bfr[4];
#pragma unroll
    for (int i = 0; i < 4; ++i)
      af[i] = *(const bf16x8*)(lA + (wr * 64 + i * 16 + (lane & 15)) * 32 + (lane >> 4) * 8);
#pragma unroll
    for (int j = 0; j < 4; ++j)
      bfr[j] = *(const bf16x8*)(lB + (wc * 64 + j * 16 + (lane & 15)) * 32 + (lane >> 4) * 8);
#pragma unroll
    for (int i = 0; i < 4; ++i)
#pragma unroll
      for (int j = 0; j < 4; ++j)
        acc[i][j] = __builtin_amdgcn_mfma_f32_16x16x32_bf16(af[i], bfr[j], acc[i][j], 0, 0, 0);
    __syncthreads();
  }
  const int hi = lane >> 4, ccol = lane & 15;
#pragma unroll
  for (int i = 0; i < 4; ++i) {
    int row = m0 + wr * 64 + i * 16 + hi * 4;
#pragma unroll
    for (int j = 0; j < 4; ++j) {
      int col = n0 + wc * 64 + j * 16 + ccol;
      if (col >= N) continue;
      float bv = bias ? bias[col] : 0.f;
#pragma unroll
      for (int rg = 0; rg < 4; ++rg) {
        int r = row + rg;
        float v = acc[i][j][rg] + bv;
        if (EPI == 0) Cf[(size_t)r * ldc + col] = v;
        else          Cb[(size_t)r * ldc + col] = f2bf(v < 0.f ? 0.f : v);
      }
    }
  }
}

// ---------------- fused: persistent GRU scan (blocks 0..24) + helper GEMM ----------------
// Workers: barrier-free scan — partials zero-polled, h sentinel-polled (0xFFFF prefill).
// Helpers (blocks >= 25): ticketed 128-row GEMM gated on per-layer done-counter.
// HEPI 0: fp32+bias (xg).  HEPI 2: exp row-permuted + per-wave row partials (logits).
template <int HEPI>
__global__ __launch_bounds__(512, 1) void k_fused(
    const float* __restrict__ xg, const short* __restrict__ UT,
    const float* __restrict__ br, float* __restrict__ hF,
    const short* __restrict__ hInit, short* __restrict__ hSeq,
    float* __restrict__ SpartL, int* __restrict__ wDone,
    const short* __restrict__ gA, const short* __restrict__ gBT,
    const float* __restrict__ gbias, float* __restrict__ gCf,
    float* __restrict__ gPp, int gN, int gldc, int gNT, int gNtiles,
    int* __restrict__ tcnt, const int* __restrict__ hGate) {
  __shared__ __align__(16) char smem[159744];
  const int tid = threadIdx.x, wid = tid >> 6, lane = tid & 63;
  const int hi = lane >> 4, ccol = lane & 15;

  if (blockIdx.x < NBLK) {
    // ================= WORKER: barrier-free scan =================
    short* uT    = (short*)smem;               // [96][808]
    float* sSum  = (float*)(smem + 155136);    // [128]
    short* hTile = (short*)(smem + 155648);    // [64][32]
    const int bid = blockIdx.x, c0 = bid * 32;
    const int rt = wid & 3, ch = wid >> 2;
    for (int idx = tid; idx < 96 * 100; idx += 512) {
      int rr = idx / 100, chk = idx % 100;
      int grow = (rr >> 5) * HH + c0 + (rr & 31);
      *(bf16x8*)(uT + rr * 808 + chk * 8) = *(const bf16x8*)(UT + (size_t)grow * HH + chk * 8);
    }
    const int crow = rt * 16 + hi * 4;
    const int gcol = c0 + ch * 16 + ccol;
    const int arow = rt * 16 + ccol;
    const short* uz = uT + (0 * 32 + ch * 16 + ccol) * 808;
    const short* ur = uT + (1 * 32 + ch * 16 + ccol) * 808;
    const short* uh = uT + (2 * 32 + ch * 16 + ccol) * 808;
    f32x4 hfr;
#pragma unroll
    for (int rg = 0; rg < 4; ++rg) hfr[rg] = hF[(crow + rg) * HH + gcol];
    const float brz = br[gcol], brr = br[HH + gcol], brh = br[2 * HH + gcol];
    float xzv[4], xrv[4], xhv[4];
#pragma unroll
    for (int rg = 0; rg < 4; ++rg) {
      const float* xrow = xg + ((size_t)(crow + rg)) * N3H;
      xzv[rg] = xrow[gcol];
      xrv[rg] = xrow[HH + gcol];
      xhv[rg] = xrow[2 * HH + gcol];
    }
    __syncthreads();   // uT staged

#pragma unroll 1
    for (int t = 0; t < TT; ++t) {
      // ---- phase 1: sentinel-poll h(t-1) (detect == fetch), MFMA, exp, publish ----
      const short* hPrev = (t == 0) ? hInit : hSeq + (size_t)(t - 1) * BB * HH;
      bf16x8 areg[25];
      {
        bool ok; int guard = 0;
        do {
#pragma unroll
          for (int kt = 0; kt < 25; ++kt)
            areg[kt] = load16_cc_nw(hPrev + arow * HH + kt * 32 + hi * 8);
          asm volatile("s_waitcnt vmcnt(0)" ::: "memory");
          __builtin_amdgcn_sched_barrier(0);   // rule-18 fence: checks AFTER the wait
          int bad = 0;
#pragma unroll
          for (int kt = 0; kt < 25; ++kt) {
            int4v w = __builtin_bit_cast(int4v, areg[kt]);
            bad |= (w.x == -1) | (w.y == -1) | (w.z == -1) | (w.w == -1);
          }
          ok = __all(bad == 0);
          if (!ok) __builtin_amdgcn_s_sleep(1);
        } while (!ok && ++guard < (1 << 18));
      }
      __builtin_amdgcn_sched_barrier(0);       // MFMAs strictly after the final wait
      f32x4 az = {}, ar = {}, ah = {};
#pragma unroll
      for (int kt = 0; kt < 25; ++kt) {
        const int o = kt * 32 + hi * 8;
        az = __builtin_amdgcn_mfma_f32_16x16x32_bf16(areg[kt], *(const bf16x8*)(uz + o), az, 0, 0, 0);
        ar = __builtin_amdgcn_mfma_f32_16x16x32_bf16(areg[kt], *(const bf16x8*)(ur + o), ar, 0, 0, 0);
        ah = __builtin_amdgcn_mfma_f32_16x16x32_bf16(areg[kt], *(const bf16x8*)(uh + o), ah, 0, 0, 0);
      }
      float ez[4], er[4], rh[4];
      float* sb = SpartL + (size_t)t * 50 * 128;
#pragma unroll
      for (int rg = 0; rg < 4; ++rg) {
        ez[rg] = __expf(xzv[rg] + az[rg] + brz);
        er[rg] = __expf(xrv[rg] + ar[rg] + brr);
        rh[rg] = ah[rg] + brh;
        float s1 = ez[rg], s2 = er[rg];
#pragma unroll
        for (int mm = 1; mm < 16; mm <<= 1) {
          s1 += __shfl_xor(s1, mm);
          s2 += __shfl_xor(s2, mm);
        }
        if (ccol == 0) {
          const int slot = bid * 2 + ch;
          __hip_atomic_store(&sb[slot * 128 + crow + rg], s1, __ATOMIC_RELAXED, __HIP_MEMORY_SCOPE_AGENT);
          __hip_atomic_store(&sb[slot * 128 + 64 + crow + rg], s2, __ATOMIC_RELAXED, __HIP_MEMORY_SCOPE_AGENT);
        }
      }
      // ---- phase 2: zero-poll partials (exp sums > 0), reduce, gates, h stores ----
      if (tid < 128) {
        bool ok; int guard = 0; float s;
        do {
          s = 0.f; ok = true;
#pragma unroll
          for (int sl = 0; sl < 2 * NBLK; ++sl) {
            float v = __hip_atomic_load(&sb[sl * 128 + tid], __ATOMIC_RELAXED, __HIP_MEMORY_SCOPE_AGENT);
            ok &= (v != 0.f);
            s += v;
          }
          if (!ok) __builtin_amdgcn_s_sleep(1);
        } while (!ok && ++guard < (1 << 18));
        sSum[tid] = s;
      }
      __syncthreads();
#pragma unroll
      for (int rg = 0; rg < 4; ++rg) {
        int r = crow + rg;
        float z = ez[rg] / sSum[r];
        float rr2 = er[rg] / sSum[64 + r];
        float hh = tanhf(xhv[rg] + rr2 * rh[rg]);
        float hn = z * hfr[rg] + (1.f - z) * hh;
        hfr[rg] = hn;
        hTile[r * 32 + ch * 16 + ccol] = f2bf(hn);
      }
      __syncthreads();
      short* hCur = hSeq + (size_t)t * BB * HH;
      if (tid < 256) {
        int row = tid >> 2, seg = tid & 3;
        store16_cc(hCur + row * HH + c0 + seg * 8, *(const bf16x8*)(hTile + row * 32 + seg * 8));
      }
      asm volatile("s_waitcnt vmcnt(0)" ::: "memory");   // h at IC
      __syncthreads();
      if (tid == 0)
        __hip_atomic_fetch_add(wDone, 1, __ATOMIC_RELAXED, __HIP_MEMORY_SCOPE_AGENT);
      if (t + 1 < TT) {
#pragma unroll
        for (int rg = 0; rg < 4; ++rg) {   // prefetch next xg (overlaps next poll)
          const float* xrow = xg + ((size_t)(t + 1) * BB + crow + rg) * N3H;
          xzv[rg] = xrow[gcol];
          xrv[rg] = xrow[HH + gcol];
          xhv[rg] = xrow[2 * HH + gcol];
        }
      }
    }
#pragma unroll
    for (int rg = 0; rg < 4; ++rg) hF[(crow + rg) * HH + gcol] = hfr[rg];
    return;
  }

  // ================= HELPER: ticketed 128x128 GEMM, 8 waves/tile =================
  short* lA = (short*)smem;
  short* lB = (short*)(smem + 8192);
  int*   tk = (int*)(smem + 16384);
  const int wr = wid >> 1, wc = wid & 1;
  for (;;) {
    if (tid == 0)
      tk[0] = __hip_atomic_fetch_add(tcnt, 1, __ATOMIC_RELAXED, __HIP_MEMORY_SCOPE_AGENT);
    __syncthreads();
    const int t0 = tk[0];
    if (t0 >= gNtiles) break;          // uniform across block
    const int mb = t0 / gNT, nb = t0 % gNT;
    const int m0 = mb * 128, n0 = nb * 128;
    if (hGate) {   // rows of tile mb final once producing scan finished step 2mb+1
      if (tid == 0) {
        int tmax = 2 * mb + 1; if (tmax > TT - 1) tmax = TT - 1;
        const int tgt = NBLK * (tmax + 1);
        bool ok; int guard = 0;
        do {
          int v = __hip_atomic_load((int*)hGate, __ATOMIC_RELAXED, __HIP_MEMORY_SCOPE_AGENT);
          ok = (v - tgt >= 0);
          if (!ok) __builtin_amdgcn_s_sleep(2);
        } while (!ok && ++guard < (1 << 20));
      }
      __syncthreads();
    }
    f32x4 acc[2][4] = {};
    const int srow = tid >> 2, sseg = tid & 3;
    for (int kt = 0; kt < 25; ++kt) {
      const int kb = kt * 32;
      gload16(gA + (size_t)(m0 + srow) * 800 + kb + sseg * 8, (char*)lA + tid * 16);
      gload16(gBT + (size_t)(n0 + srow) * 800 + kb + sseg * 8, (char*)lB + tid * 16);
      __syncthreads();
      bf16x8 af[2], bf[4];
#pragma unroll
      for (int i = 0; i < 2; ++i)
        af[i] = *(const bf16x8*)(lA + (wr * 32 + i * 16 + (lane & 15)) * 32 + hi * 8);
#pragma unroll
      for (int j = 0; j < 4; ++j)
        bf[j] = *(const bf16x8*)(lB + (wc * 64 + j * 16 + (lane & 15)) * 32 + hi * 8);
#pragma unroll
      for (int i = 0; i < 2; ++i)
#pragma unroll
        for (int j = 0; j < 4; ++j)
          acc[i][j] = __builtin_amdgcn_mfma_f32_16x16x32_bf16(af[i], bf[j], acc[i][j], 0, 0, 0);
      __syncthreads();
    }
    if (HEPI == 2) {
#pragma unroll
      for (int i = 0; i < 2; ++i) {
        int row = m0 + wr * 32 + i * 16 + hi * 4;
#pragma unroll
        for (int rg = 0; rg < 4; ++rg) {
          int r = row + rg;
          int orow = (r & 63) * TT + (r >> 6);   // (t,b) -> (b,t)
          float part = 0.f;
#pragma unroll
          for (int j = 0; j < 4; ++j) {
            int col = n0 + wc * 64 + j * 16 + ccol;
            float v = __expf(acc[i][j][rg] + gbias[col]);
            part += v;
            gCf[(size_t)orow * gldc + col] = v;
          }
#pragma unroll
          for (int mm = 1; mm < 16; mm <<= 1) part += __shfl_xor(part, mm);
          if (ccol == 0) gPp[(size_t)orow * 512 + nb * 2 + wc] = part;
        }
      }
    } else {
#pragma unroll
      for (int i = 0; i < 2; ++i) {
        int row = m0 + wr * 32 + i * 16 + hi * 4;
#pragma unroll
        for (int j = 0; j < 4; ++j) {
          int col = n0 + wc * 64 + j * 16 + ccol;
          if (col >= gN) continue;
          float bv = gbias[col];
#pragma unroll
          for (int rg = 0; rg < 4; ++rg)
            gCf[(size_t)(row + rg) * gldc + col] = acc[i][j][rg] + bv;
        }
      }
    }
  }
}

// -------- normalize pass: sum 500 per-row partials, scale row (exp already stored) --------
__global__ __launch_bounds__(256) void k_softmax(float* __restrict__ out,
                                                 const float* __restrict__ Pp) {
  float* row = out + (size_t)blockIdx.x * VV;
  const float* pp = Pp + (size_t)blockIdx.x * 512;
  const int tid = threadIdx.x;
  __shared__ float red[4];
  float sum = 0.f;
  for (int i = tid; i < 500; i += 256) sum += pp[i];
#pragma unroll
  for (int s = 32; s >= 1; s >>= 1) sum += __shfl_xor(sum, s);
  if ((tid & 63) == 0) red[tid >> 6] = sum;
  __syncthreads();
  float inv = 1.f / (red[0] + red[1] + red[2] + red[3]);
  for (int i = tid * 4; i < VV; i += 1024) {
    float4v v = *(const float4v*)(row + i);
    v[0] *= inv; v[1] *= inv; v[2] *= inv; v[3] *= inv;
    *(float4v*)(row + i) = v;
  }
}

extern "C" void kernel_launch(void* const* d_in, const int* in_sizes, int n_in,
                              void* d_out, int out_size, void* d_ws, size_t ws_size,
                              hipStream_t stream) {
  (void)in_sizes; (void)n_in; (void)out_size; (void)ws_size;
  const int*   enc  = (const int*)d_in[0];
  const int*   dec  = (const int*)d_in[1];
  const float* embF = (const float*)d_in[2];
  const float* Wd1  = (const float*)d_in[3];
  const float* bd1  = (const float*)d_in[4];
  const float* Wf1  = (const float*)d_in[5];
  const float* Uf1  = (const float*)d_in[6];
  const float* bf1  = (const float*)d_in[7];
  const float* Wf2  = (const float*)d_in[8];
  const float* Uf2  = (const float*)d_in[9];
  const float* bf2  = (const float*)d_in[10];
  const float* embE = (const float*)d_in[11];
  const float* We1  = (const float*)d_in[12];
  const float* Ue1  = (const float*)d_in[13];
  const float* be1  = (const float*)d_in[14];
  const float* We2  = (const float*)d_in[15];
  const float* Ue2  = (const float*)d_in[16];
  const float* be2  = (const float*)d_in[17];
  const float* Wout = (const float*)d_in[18];
  const float* bout = (const float*)d_in[19];

  char* p = (char*)d_ws;
  auto alloc = [&](size_t bytes) { char* r = p; p += (bytes + 255) & ~(size_t)255; return r; };
  short* WdT = (short*)alloc((size_t)896 * 800 * 2);
  short* WTb[4]; short* UTb[4];
  for (int i = 0; i < 4; ++i) {
    WTb[i] = (short*)alloc((size_t)2432 * 800 * 2);
    UTb[i] = (short*)alloc((size_t)2400 * 800 * 2);
  }
  short* WoT = (short*)alloc((size_t)VV * 800 * 2);
  short* feA = (short*)alloc((size_t)MR * DD * 2);
  short* fe  = (short*)alloc((size_t)MR * DD * 2);
  short* ee  = (short*)alloc((size_t)MR * DD * 2);
  // --- sentinel (0xFF) region: hSeq buffers g1..e2 ---
  short* g1  = (short*)alloc((size_t)MR * HH * 2);
  short* g2s = (short*)alloc((size_t)MR * HH * 2);
  short* e1  = (short*)alloc((size_t)MR * HH * 2);
  short* e2  = (short*)alloc((size_t)MR * HH * 2);
  float* xgA = (float*)alloc((size_t)MR * N3H * 4);
  float* xgB = (float*)alloc((size_t)MR * N3H * 4);
  float* Ppart = (float*)alloc((size_t)MR * 512 * 4);
  // --- zeroed region: Spart .. tcnt ---
  float* Spart = (float*)alloc((size_t)4 * TT * 50 * 128 * 4);   // per (layer,t)
  float* hF   = (float*)alloc((size_t)BB * HH * 4);
  short* hIn0 = (short*)alloc((size_t)BB * HH * 2);
  int* hDone  = (int*)alloc((size_t)16 * 4);   // per-layer worker done-counters
  int* tcnt   = (int*)alloc((size_t)16 * 4);   // per-layer helper tickets

  hipMemsetAsync(Spart, 0, (char*)(tcnt + 16) - (char*)Spart, stream);
  hipMemsetAsync(g1, 0xFF, (char*)(e2 + (size_t)MR * HH) - (char*)g1, stream);

  dim3 tb(32, 8);
  k_cast_transpose<<<dim3(25, 25), tb, 0, stream>>>(Wd1, WdT, 800, 800);
  const float* Ws[4] = {Wf1, Wf2, We1, We2};
  const float* Us[4] = {Uf1, Uf2, Ue1, Ue2};
  for (int i = 0; i < 4; ++i) {
    k_cast_transpose<<<dim3(75, 25), tb, 0, stream>>>(Ws[i], WTb[i], 800, 2400);
    k_cast_transpose<<<dim3(75, 25), tb, 0, stream>>>(Us[i], UTb[i], 800, 2400);
  }
  k_cast_transpose<<<dim3(1000, 25), tb, 0, stream>>>(Wout, WoT, 800, VV);
  k_gather<<<MR, 128, 0, stream>>>(enc, embF, feA);
  k_gather<<<MR, 128, 0, stream>>>(dec, embE, ee);
  // fe = relu(feA @ Wd1 + bd1) -> bf16 ; then xg(layer0) = fe @ Wf1 + bf1[0] -> xgA
  k_gemm<1><<<dim3(7, 24), 256, 0, stream>>>(feA, WdT, bd1, nullptr, fe, 800, 800, 800);
  k_gemm<0><<<dim3(19, 24), 256, 0, stream>>>(fe, WTb[0], bf1, xgA, nullptr, N3H, 800, N3H);

  const float* bs[4] = {bf1, bf2, be1, be2};
  short* hSeqL[4] = {g1, g2s, e1, e2};
  float* xgR[4] = {xgA, xgB, xgA, xgB};      // scan l reads
  // helper during dispatch l computes layer l+1's xg (or logits at l=3)
  const short* hA[4]    = {g1, ee, e1, e2};
  const short* hBT[4]   = {WTb[1], WTb[2], WTb[3], WoT};
  const float* hBias[4] = {bs[1], bs[2], bs[3], bout};
  float* hOut[4] = {xgB, xgA, xgB, (float*)d_out};
  const int* hGate[4] = {&hDone[0], nullptr, &hDone[2], &hDone[3]};

  for (int l = 0; l < 4; ++l) {
    const short* hInit = (l == 0) ? hIn0 : hSeqL[l - 1] + (size_t)(TT - 1) * BB * HH;
    float* SpL = Spart + (size_t)l * TT * 50 * 128;
    if (l < 3) {
      k_fused<0><<<256, 512, 0, stream>>>(xgR[l], UTb[l], bs[l] + N3H, hF, hInit, hSeqL[l],
                                          SpL, &hDone[l],
                                          hA[l], hBT[l], hBias[l], hOut[l], nullptr,
                                          N3H, N3H, 19, 24 * 19, &tcnt[l], hGate[l]);
    } else {
      k_fused<2><<<256, 512, 0, stream>>>(xgR[l], UTb[l], bs[l] + N3H, hF, hInit, hSeqL[l],
                                          SpL, &hDone[l],
                                          hA[l], hBT[l], hBias[l], hOut[l], Ppart,
                                          VV, VV, 250, 24 * 250, &tcnt[l], hGate[l]);
    }
  }
  k_softmax<<<MR, 256, 0, stream>>>((float*)d_out, Ppart);
}

// Round 14
// 2301.552 us; speedup vs baseline: 1.1756x; 1.1756x over previous
//
#include <hip/hip_runtime.h>

#define DD 800
#define HH 800
#define BB 64
#define TT 48
#define N3H 2400
#define VV 32000
#define MR (TT*BB)   // 3072 rows, time-major (t*BB + b)
#define NBLK 25      // scan workers: 25 x 32 H-columns; blocks >= NBLK are GEMM helpers

typedef __attribute__((ext_vector_type(8))) short bf16x8;
typedef __attribute__((ext_vector_type(4))) float f32x4;
typedef __attribute__((ext_vector_type(4))) float float4v;
typedef __attribute__((address_space(1))) const unsigned int as1_uint;
typedef __attribute__((address_space(3))) unsigned int as3_uint;

__device__ __forceinline__ short f2bf(float f) {
  unsigned int u = __builtin_bit_cast(unsigned int, f);
  u = (u + 0x7fffu + ((u >> 16) & 1u)) >> 16;
  return (short)(unsigned short)u;
}

__device__ __forceinline__ void gload16(const void* g, void* l) {
  __builtin_amdgcn_global_load_lds((as1_uint*)g, (as3_uint*)l, 16, 0, 0);
}

// device-coherent 16B store: write-through to IC (visible chip-wide after vmcnt drain).
__device__ __forceinline__ void store16_cc(short* p, bf16x8 v) {
  asm volatile("global_store_dwordx4 %0, %1, off sc0 sc1" :: "v"(p), "v"(v));
}

// ---------------- transpose + cast fp32 [K][N] -> bf16 [N][K] ----------------
__global__ void k_cast_transpose(const float* __restrict__ src, short* __restrict__ dst,
                                 int K, int N) {
  __shared__ float tile[32][33];
  int n0 = blockIdx.x * 32, k0 = blockIdx.y * 32;
  int tx = threadIdx.x, ty = threadIdx.y;   // (32,8)
#pragma unroll
  for (int i = 0; i < 4; ++i) {
    int k = k0 + ty + i * 8, n = n0 + tx;
    if (k < K && n < N) tile[ty + i * 8][tx] = src[(size_t)k * N + n];
  }
  __syncthreads();
#pragma unroll
  for (int i = 0; i < 4; ++i) {
    int n = n0 + ty + i * 8, k = k0 + tx;
    if (n < N && k < K) dst[(size_t)n * K + k] = f2bf(tile[tx][ty + i * 8]);
  }
}

// ---------------- gather embedding rows -> bf16, time-major ----------------
__global__ void k_gather(const int* __restrict__ ids, const float* __restrict__ emb,
                         short* __restrict__ out) {
  int r = blockIdx.x;            // r = t*BB + b
  int t = r >> 6, b = r & 63;
  int id = ids[b * TT + t];
  int i = threadIdx.x;
  if (i < 100) {
    const float* s = emb + (size_t)id * DD + i * 8;
    float4v v0 = *(const float4v*)s;
    float4v v1 = *(const float4v*)(s + 4);
    bf16x8 o;
    o[0] = f2bf(v0[0]); o[1] = f2bf(v0[1]); o[2] = f2bf(v0[2]); o[3] = f2bf(v0[3]);
    o[4] = f2bf(v1[0]); o[5] = f2bf(v1[1]); o[6] = f2bf(v1[2]); o[7] = f2bf(v1[3]);
    *(bf16x8*)(out + (size_t)r * DD + i * 8) = o;
  }
}

// ---------------- standalone bf16 GEMM (prologue only) ----------------
// EPI 0: fp32 store + bias (xg).  EPI 1: relu -> bf16 (fe).
template <int EPI>
__global__ __launch_bounds__(256) void k_gemm(const short* __restrict__ A,
                                              const short* __restrict__ BT,
                                              const float* __restrict__ bias,
                                              float* __restrict__ Cf,
                                              short* __restrict__ Cb,
                                              int N, int K, int ldc) {
  __shared__ short lA[128 * 32];
  __shared__ short lB[128 * 32];
  const int tid = threadIdx.x, wid = tid >> 6, lane = tid & 63;
  const int m0 = blockIdx.y * 128, n0 = blockIdx.x * 128;
  const int wr = wid >> 1, wc = wid & 1;
  f32x4 acc[4][4] = {};
  for (int kt = 0; kt < K / 32; ++kt) {
    const int kb = kt * 32;
#pragma unroll
    for (int rr = 0; rr < 2; ++rr) {
      int s = rr * 256 + tid;
      gload16(A + (size_t)(m0 + (s >> 2)) * K + kb + (s & 3) * 8, (char*)lA + s * 16);
      gload16(BT + (size_t)(n0 + (s >> 2)) * K + kb + (s & 3) * 8, (char*)lB + s * 16);
    }
    __syncthreads();
    bf16x8 af[4], bfr[4];
#pragma unroll
    for (int i = 0; i < 4; ++i)
      af[i] = *(const bf16x8*)(lA + (wr * 64 + i * 16 + (lane & 15)) * 32 + (lane >> 4) * 8);
#pragma unroll
    for (int j = 0; j < 4; ++j)
      bfr[j] = *(const bf16x8*)(lB + (wc * 64 + j * 16 + (lane & 15)) * 32 + (lane >> 4) * 8);
#pragma unroll
    for (int i = 0; i < 4; ++i)
#pragma unroll
      for (int j = 0; j < 4; ++j)
        acc[i][j] = __builtin_amdgcn_mfma_f32_16x16x32_bf16(af[i], bfr[j], acc[i][j], 0, 0, 0);
    __syncthreads();
  }
  const int hi = lane >> 4, ccol = lane & 15;
#pragma unroll
  for (int i = 0; i < 4; ++i) {
    int row = m0 + wr * 64 + i * 16 + hi * 4;
#pragma unroll
    for (int j = 0; j < 4; ++j) {
      int col = n0 + wc * 64 + j * 16 + ccol;
      if (col >= N) continue;
      float bv = bias ? bias[col] : 0.f;
#pragma unroll
      for (int rg = 0; rg < 4; ++rg) {
        int r = row + rg;
        float v = acc[i][j][rg] + bv;
        if (EPI == 0) Cf[(size_t)r * ldc + col] = v;
        else          Cb[(size_t)r * ldc + col] = f2bf(v < 0.f ? 0.f : v);
      }
    }
  }
}

// ------- fence-free grid barrier (R7): flag-store arrive + 25-lane poll -------
__device__ __forceinline__ void bar_sync(int* flags, int ep, int tid) {
  asm volatile("s_waitcnt vmcnt(0)" ::: "memory");   // per-wave store drain
  __syncthreads();
  if (tid == 0)
    __hip_atomic_store(&flags[blockIdx.x * 32], ep, __ATOMIC_RELAXED, __HIP_MEMORY_SCOPE_AGENT);
  if (tid < 64) {
    bool ok;
    do {
      int v = ep;
      if (tid < NBLK)
        v = __hip_atomic_load(&flags[tid * 32], __ATOMIC_RELAXED, __HIP_MEMORY_SCOPE_AGENT);
      ok = __all(v - ep >= 0);
      if (!ok) __builtin_amdgcn_s_sleep(1);
    } while (!ok);
  }
  __syncthreads();
}

// ---------------- fused: persistent GRU scan (blocks 0..24) + helper GEMM ----------------
// Workers: exact R11/R7 structure (best proven). Helpers (blocks >= 25): ticketed
// 128x128 GEMM with K=160 staging (5 latency windows/tile instead of 25); tile m
// polls scan flags (target pollBase + 2*tmax + 2). HEPI 0: fp32+bias (xg).
// HEPI 2: exp(v+bias) row-permuted NT-store to d_out + per-wave row partials.
template <int HEPI>
__global__ __launch_bounds__(512, 1) void k_fused(
    const float* __restrict__ xg, const short* __restrict__ UT,
    const float* __restrict__ br, float* __restrict__ hF,
    const short* __restrict__ hInit, short* __restrict__ hSeq,
    float* __restrict__ Spart, int* __restrict__ flags, int ep0,
    const short* __restrict__ gA, const short* __restrict__ gBT,
    const float* __restrict__ gbias, float* __restrict__ gCf,
    float* __restrict__ gPp, int gN, int gldc, int gNT, int gNtiles,
    int* __restrict__ tcnt, int pollBase) {
  __shared__ __align__(16) char smem[159744];
  const int tid = threadIdx.x, wid = tid >> 6, lane = tid & 63;
  const int hi = lane >> 4, ccol = lane & 15;

  if (blockIdx.x < NBLK) {
    // ================= WORKER: R11 scan, verbatim =================
    short* uT    = (short*)smem;               // [96][808]
    float* sSum  = (float*)(smem + 155136);    // [128]
    short* hTile = (short*)(smem + 155648);    // [64][32]
    const int bid = blockIdx.x, c0 = bid * 32;
    const int rt = wid & 3, ch = wid >> 2;
    for (int idx = tid; idx < 96 * 100; idx += 512) {
      int rr = idx / 100, chk = idx % 100;
      int grow = (rr >> 5) * HH + c0 + (rr & 31);
      *(bf16x8*)(uT + rr * 808 + chk * 8) = *(const bf16x8*)(UT + (size_t)grow * HH + chk * 8);
    }
    const int crow = rt * 16 + hi * 4;
    const int gcol = c0 + ch * 16 + ccol;
    const int arow = rt * 16 + ccol;
    const short* uz = uT + (0 * 32 + ch * 16 + ccol) * 808;
    const short* ur = uT + (1 * 32 + ch * 16 + ccol) * 808;
    const short* uh = uT + (2 * 32 + ch * 16 + ccol) * 808;
    f32x4 hfr;
#pragma unroll
    for (int rg = 0; rg < 4; ++rg) hfr[rg] = hF[(crow + rg) * HH + gcol];
    const float brz = br[gcol], brr = br[HH + gcol], brh = br[2 * HH + gcol];
    int ep = ep0;
    float xzv[4], xrv[4], xhv[4];
#pragma unroll
    for (int rg = 0; rg < 4; ++rg) {
      const float* xrow = xg + ((size_t)(crow + rg)) * N3H;
      xzv[rg] = xrow[gcol];
      xrv[rg] = xrow[HH + gcol];
      xhv[rg] = xrow[2 * HH + gcol];
    }
    __syncthreads();

#pragma unroll 1
    for (int t = 0; t < TT; ++t) {
      const short* hPrev = (t == 0) ? hInit : hSeq + (size_t)(t - 1) * BB * HH;
      bf16x8 areg[25];
#pragma unroll
      for (int kt = 0; kt < 25; ++kt)
        areg[kt] = *(const bf16x8*)(hPrev + arow * HH + kt * 32 + hi * 8);
      f32x4 az = {}, ar = {}, ah = {};
#pragma unroll
      for (int kt = 0; kt < 25; ++kt) {
        const int o = kt * 32 + hi * 8;
        az = __builtin_amdgcn_mfma_f32_16x16x32_bf16(areg[kt], *(const bf16x8*)(uz + o), az, 0, 0, 0);
        ar = __builtin_amdgcn_mfma_f32_16x16x32_bf16(areg[kt], *(const bf16x8*)(ur + o), ar, 0, 0, 0);
        ah = __builtin_amdgcn_mfma_f32_16x16x32_bf16(areg[kt], *(const bf16x8*)(uh + o), ah, 0, 0, 0);
      }
      float ez[4], er[4], rh[4];
      float* sb = Spart + (size_t)t * 50 * 128;
#pragma unroll
      for (int rg = 0; rg < 4; ++rg) {
        ez[rg] = __expf(xzv[rg] + az[rg] + brz);
        er[rg] = __expf(xrv[rg] + ar[rg] + brr);
        rh[rg] = ah[rg] + brh;
        float s1 = ez[rg], s2 = er[rg];
#pragma unroll
        for (int mm = 1; mm < 16; mm <<= 1) {
          s1 += __shfl_xor(s1, mm);
          s2 += __shfl_xor(s2, mm);
        }
        if (ccol == 0) {
          const int slot = bid * 2 + ch;
          __hip_atomic_store(&sb[slot * 128 + crow + rg], s1, __ATOMIC_RELAXED, __HIP_MEMORY_SCOPE_AGENT);
          __hip_atomic_store(&sb[slot * 128 + 64 + crow + rg], s2, __ATOMIC_RELAXED, __HIP_MEMORY_SCOPE_AGENT);
        }
      }
      bar_sync(flags, ++ep, tid);
      if (tid < 128) {
        float s = 0.f;
#pragma unroll
        for (int sl = 0; sl < 2 * NBLK; ++sl)
          s += __hip_atomic_load(&sb[sl * 128 + tid], __ATOMIC_RELAXED, __HIP_MEMORY_SCOPE_AGENT);
        sSum[tid] = s;
      }
      __syncthreads();
#pragma unroll
      for (int rg = 0; rg < 4; ++rg) {
        int r = crow + rg;
        float z = ez[rg] / sSum[r];
        float rr2 = er[rg] / sSum[64 + r];
        float hh = tanhf(xhv[rg] + rr2 * rh[rg]);
        float hn = z * hfr[rg] + (1.f - z) * hh;
        hfr[rg] = hn;
        hTile[r * 32 + ch * 16 + ccol] = f2bf(hn);
      }
      __syncthreads();
      short* hCur = hSeq + (size_t)t * BB * HH;
      if (tid < 256) {
        int row = tid >> 2, seg = tid & 3;
        store16_cc(hCur + row * HH + c0 + seg * 8, *(const bf16x8*)(hTile + row * 32 + seg * 8));
      }
      if (t + 1 < TT) {
#pragma unroll
        for (int rg = 0; rg < 4; ++rg) {
          const float* xrow = xg + ((size_t)(t + 1) * BB + crow + rg) * N3H;
          xzv[rg] = xrow[gcol];
          xrv[rg] = xrow[HH + gcol];
          xhv[rg] = xrow[2 * HH + gcol];
        }
      }
      bar_sync(flags, ++ep, tid);
    }
#pragma unroll
    for (int rg = 0; rg < 4; ++rg) hF[(crow + rg) * HH + gcol] = hfr[rg];
    return;
  }

  // ========= HELPER: ticketed 128x128 GEMM, K=160 staging (5 windows/tile) =========
  short* lA = (short*)smem;                 // [128][160] bf16 = 40960 B
  short* lB = (short*)(smem + 40960);       // [128][160]
  int*   tk = (int*)(smem + 81920);
  const int wr = wid >> 1, wc = wid & 1;
  for (;;) {
    if (tid == 0)
      tk[0] = __hip_atomic_fetch_add(tcnt, 1, __ATOMIC_RELAXED, __HIP_MEMORY_SCOPE_AGENT);
    __syncthreads();
    const int t0 = tk[0];
    if (t0 >= gNtiles) break;          // uniform across block
    const int mb = t0 / gNT, nb = t0 % gNT;
    const int m0 = mb * 128, n0 = nb * 128;
    // poll: rows of tile mb are final once scan step 2*mb+1 is published
    {
      int tmax = 2 * mb + 1; if (tmax > TT - 1) tmax = TT - 1;
      const int ft = pollBase + 2 * tmax + 2;
      bool ok;
      do {
        int v = ft;
        if (lane < NBLK)
          v = __hip_atomic_load(&flags[lane * 32], __ATOMIC_RELAXED, __HIP_MEMORY_SCOPE_AGENT);
        ok = __all(v - ft >= 0);
        if (!ok) __builtin_amdgcn_s_sleep(2);
      } while (!ok);
      asm volatile("" ::: "memory");
    }
    f32x4 acc[2][4] = {};
#pragma unroll 1
    for (int kt = 0; kt < 5; ++kt) {
      const int kb = kt * 160;
#pragma unroll
      for (int i = 0; i < 5; ++i) {
        int c = tid + 512 * i;          // 16B chunk id, 0..2559 (row-major, 20/row)
        int row = c / 20, seg = c % 20;
        gload16(gA + (size_t)(m0 + row) * 800 + kb + seg * 8, (char*)lA + c * 16);
        gload16(gBT + (size_t)(n0 + row) * 800 + kb + seg * 8, (char*)lB + c * 16);
      }
      __syncthreads();
#pragma unroll
      for (int kk = 0; kk < 5; ++kk) {
        bf16x8 af[2], bf[4];
#pragma unroll
        for (int i = 0; i < 2; ++i)
          af[i] = *(const bf16x8*)(lA + (wr * 32 + i * 16 + (lane & 15)) * 160 + kk * 32 + hi * 8);
#pragma unroll
        for (int j = 0; j < 4; ++j)
          bf[j] = *(const bf16x8*)(lB + (wc * 64 + j * 16 + (lane & 15)) * 160 + kk * 32 + hi * 8);
#pragma unroll
        for (int i = 0; i < 2; ++i)
#pragma unroll
          for (int j = 0; j < 4; ++j)
            acc[i][j] = __builtin_amdgcn_mfma_f32_16x16x32_bf16(af[i], bf[j], acc[i][j], 0, 0, 0);
      }
      __syncthreads();
    }
    if (HEPI == 2) {
#pragma unroll
      for (int i = 0; i < 2; ++i) {
        int row = m0 + wr * 32 + i * 16 + hi * 4;
#pragma unroll
        for (int rg = 0; rg < 4; ++rg) {
          int r = row + rg;
          int orow = (r & 63) * TT + (r >> 6);   // (t,b) -> (b,t)
          float part = 0.f;
#pragma unroll
          for (int j = 0; j < 4; ++j) {
            int col = n0 + wc * 64 + j * 16 + ccol;
            float v = __expf(acc[i][j][rg] + gbias[col]);
            part += v;
            __builtin_nontemporal_store(v, &gCf[(size_t)orow * gldc + col]);  // NT: keep Wout IC-resident
          }
#pragma unroll
          for (int mm = 1; mm < 16; mm <<= 1) part += __shfl_xor(part, mm);
          if (ccol == 0) __builtin_nontemporal_store(part, &gPp[(size_t)orow * 512 + nb * 2 + wc]);
        }
      }
    } else {
#pragma unroll
      for (int i = 0; i < 2; ++i) {
        int row = m0 + wr * 32 + i * 16 + hi * 4;
#pragma unroll
        for (int j = 0; j < 4; ++j) {
          int col = n0 + wc * 64 + j * 16 + ccol;
          if (col >= gN) continue;
          float bv = gbias[col];
#pragma unroll
          for (int rg = 0; rg < 4; ++rg)
            gCf[(size_t)(row + rg) * gldc + col] = acc[i][j][rg] + bv;
        }
      }
    }
  }
}

// -------- normalize pass: sum 500 per-row partials, scale row (exp already stored) --------
__global__ __launch_bounds__(256) void k_softmax(float* __restrict__ out,
                                                 const float* __restrict__ Pp) {
  float* row = out + (size_t)blockIdx.x * VV;
  const float* pp = Pp + (size_t)blockIdx.x * 512;
  const int tid = threadIdx.x;
  __shared__ float red[4];
  float sum = 0.f;
  for (int i = tid; i < 500; i += 256) sum += pp[i];
#pragma unroll
  for (int s = 32; s >= 1; s >>= 1) sum += __shfl_xor(sum, s);
  if ((tid & 63) == 0) red[tid >> 6] = sum;
  __syncthreads();
  float inv = 1.f / (red[0] + red[1] + red[2] + red[3]);
  for (int i = tid * 4; i < VV; i += 1024) {
    float4v v = *(const float4v*)(row + i);
    v[0] *= inv; v[1] *= inv; v[2] *= inv; v[3] *= inv;
    *(float4v*)(row + i) = v;
  }
}

extern "C" void kernel_launch(void* const* d_in, const int* in_sizes, int n_in,
                              void* d_out, int out_size, void* d_ws, size_t ws_size,
                              hipStream_t stream) {
  (void)in_sizes; (void)n_in; (void)out_size; (void)ws_size;
  const int*   enc  = (const int*)d_in[0];
  const int*   dec  = (const int*)d_in[1];
  const float* embF = (const float*)d_in[2];
  const float* Wd1  = (const float*)d_in[3];
  const float* bd1  = (const float*)d_in[4];
  const float* Wf1  = (const float*)d_in[5];
  const float* Uf1  = (const float*)d_in[6];
  const float* bf1  = (const float*)d_in[7];
  const float* Wf2  = (const float*)d_in[8];
  const float* Uf2  = (const float*)d_in[9];
  const float* bf2  = (const float*)d_in[10];
  const float* embE = (const float*)d_in[11];
  const float* We1  = (const float*)d_in[12];
  const float* Ue1  = (const float*)d_in[13];
  const float* be1  = (const float*)d_in[14];
  const float* We2  = (const float*)d_in[15];
  const float* Ue2  = (const float*)d_in[16];
  const float* be2  = (const float*)d_in[17];
  const float* Wout = (const float*)d_in[18];
  const float* bout = (const float*)d_in[19];

  char* p = (char*)d_ws;
  auto alloc = [&](size_t bytes) { char* r = p; p += (bytes + 255) & ~(size_t)255; return r; };
  short* WdT = (short*)alloc((size_t)896 * 800 * 2);
  short* WTb[4]; short* UTb[4];
  for (int i = 0; i < 4; ++i) {
    WTb[i] = (short*)alloc((size_t)2432 * 800 * 2);
    UTb[i] = (short*)alloc((size_t)2400 * 800 * 2);
  }
  short* WoT = (short*)alloc((size_t)VV * 800 * 2);
  short* feA = (short*)alloc((size_t)MR * DD * 2);
  short* fe  = (short*)alloc((size_t)MR * DD * 2);
  short* ee  = (short*)alloc((size_t)MR * DD * 2);
  short* g1  = (short*)alloc((size_t)MR * HH * 2);
  short* g2s = (short*)alloc((size_t)MR * HH * 2);   // layer-1 hSeq scratch
  short* e1  = (short*)alloc((size_t)MR * HH * 2);
  short* e2  = (short*)alloc((size_t)MR * HH * 2);
  float* xgA = (float*)alloc((size_t)MR * N3H * 4);
  float* xgB = (float*)alloc((size_t)MR * N3H * 4);
  float* Ppart = (float*)alloc((size_t)MR * 512 * 4);
  float* Spart = (float*)alloc((size_t)TT * 50 * 128 * 4);
  // --- zeroed-at-launch region: hF .. tcnt ---
  float* hF   = (float*)alloc((size_t)BB * HH * 4);
  short* hIn0 = (short*)alloc((size_t)BB * HH * 2);
  int* flags  = (int*)alloc((size_t)NBLK * 32 * 4);
  int* tcnt   = (int*)alloc((size_t)16 * 4);

  size_t tail = (char*)(tcnt + 16) - (char*)hF;
  hipMemsetAsync(hF, 0, tail, stream);

  dim3 tb(32, 8);
  k_cast_transpose<<<dim3(25, 25), tb, 0, stream>>>(Wd1, WdT, 800, 800);
  const float* Ws[4] = {Wf1, Wf2, We1, We2};
  const float* Us[4] = {Uf1, Uf2, Ue1, Ue2};
  for (int i = 0; i < 4; ++i) {
    k_cast_transpose<<<dim3(75, 25), tb, 0, stream>>>(Ws[i], WTb[i], 800, 2400);
    k_cast_transpose<<<dim3(75, 25), tb, 0, stream>>>(Us[i], UTb[i], 800, 2400);
  }
  k_cast_transpose<<<dim3(1000, 25), tb, 0, stream>>>(Wout, WoT, 800, VV);
  k_gather<<<MR, 128, 0, stream>>>(enc, embF, feA);
  k_gather<<<MR, 128, 0, stream>>>(dec, embE, ee);
  // fe = relu(feA @ Wd1 + bd1) -> bf16 ; then xg(layer0) = fe @ Wf1 + bf1[0] -> xgA
  k_gemm<1><<<dim3(7, 24), 256, 0, stream>>>(feA, WdT, bd1, nullptr, fe, 800, 800, 800);
  k_gemm<0><<<dim3(19, 24), 256, 0, stream>>>(fe, WTb[0], bf1, xgA, nullptr, N3H, 800, N3H);

  const float* bs[4] = {bf1, bf2, be1, be2};
  short* hSeqL[4] = {g1, g2s, e1, e2};
  float* xgR[4] = {xgA, xgB, xgA, xgB};      // scan l reads
  // helper during scan l computes layer l+1's xg (or logits at l=3)
  const short* hA[4]   = {g1, ee, e1, e2};
  const short* hBT[4]  = {WTb[1], WTb[2], WTb[3], WoT};
  const float* hBias[4]= {bs[1], bs[2], bs[3], bout};
  float* hOut[4] = {xgB, xgA, xgB, (float*)d_out};
  int   hPoll[4] = {0 * 96, -1000000, 2 * 96, 3 * 96};   // l=1 input (ee) needs no poll

  for (int l = 0; l < 4; ++l) {
    const short* hInit = (l == 0) ? hIn0 : hSeqL[l - 1] + (size_t)(TT - 1) * BB * HH;
    if (l < 3) {
      k_fused<0><<<256, 512, 0, stream>>>(xgR[l], UTb[l], bs[l] + N3H, hF, hInit, hSeqL[l],
                                          Spart, flags, l * 2 * TT,
                                          hA[l], hBT[l], hBias[l], hOut[l], nullptr,
                                          N3H, N3H, 19, 24 * 19, &tcnt[l], hPoll[l]);
    } else {
      k_fused<2><<<256, 512, 0, stream>>>(xgR[l], UTb[l], bs[l] + N3H, hF, hInit, hSeqL[l],
                                          Spart, flags, l * 2 * TT,
                                          hA[l], hBT[l], hBias[l], hOut[l], Ppart,
                                          VV, VV, 250, 24 * 250, &tcnt[l], hPoll[l]);
    }
  }
  k_softmax<<<MR, 256, 0, stream>>>((float*)d_out, Ppart);
}

// Round 15
// 2271.476 us; speedup vs baseline: 1.1911x; 1.0132x over previous
//
#include <hip/hip_runtime.h>

#define DD 800
#define HH 800
#define BB 64
#define TT 48
#define N3H 2400
#define VV 32000
#define MR (TT*BB)   // 3072 rows, time-major (t*BB + b)
#define NBLK 25      // scan workers: 25 x 32 H-columns; blocks >= NBLK are GEMM helpers

typedef __attribute__((ext_vector_type(8))) short bf16x8;
typedef __attribute__((ext_vector_type(4))) float f32x4;
typedef __attribute__((ext_vector_type(4))) float float4v;
typedef __attribute__((address_space(1))) const unsigned int as1_uint;
typedef __attribute__((address_space(3))) unsigned int as3_uint;

__device__ __forceinline__ short f2bf(float f) {
  unsigned int u = __builtin_bit_cast(unsigned int, f);
  u = (u + 0x7fffu + ((u >> 16) & 1u)) >> 16;
  return (short)(unsigned short)u;
}

__device__ __forceinline__ void gload16(const void* g, void* l) {
  __builtin_amdgcn_global_load_lds((as1_uint*)g, (as3_uint*)l, 16, 0, 0);
}

// device-coherent 16B store: write-through to IC (visible chip-wide after vmcnt drain).
__device__ __forceinline__ void store16_cc(short* p, bf16x8 v) {
  asm volatile("global_store_dwordx4 %0, %1, off sc0 sc1" :: "v"(p), "v"(v));
}

// ---------------- transpose + cast fp32 [K][N] -> bf16 [N][K] ----------------
__global__ void k_cast_transpose(const float* __restrict__ src, short* __restrict__ dst,
                                 int K, int N) {
  __shared__ float tile[32][33];
  int n0 = blockIdx.x * 32, k0 = blockIdx.y * 32;
  int tx = threadIdx.x, ty = threadIdx.y;   // (32,8)
#pragma unroll
  for (int i = 0; i < 4; ++i) {
    int k = k0 + ty + i * 8, n = n0 + tx;
    if (k < K && n < N) tile[ty + i * 8][tx] = src[(size_t)k * N + n];
  }
  __syncthreads();
#pragma unroll
  for (int i = 0; i < 4; ++i) {
    int n = n0 + ty + i * 8, k = k0 + tx;
    if (n < N && k < K) dst[(size_t)n * K + k] = f2bf(tile[tx][ty + i * 8]);
  }
}

// ---------------- gather embedding rows -> bf16, time-major ----------------
__global__ void k_gather(const int* __restrict__ ids, const float* __restrict__ emb,
                         short* __restrict__ out) {
  int r = blockIdx.x;            // r = t*BB + b
  int t = r >> 6, b = r & 63;
  int id = ids[b * TT + t];
  int i = threadIdx.x;
  if (i < 100) {
    const float* s = emb + (size_t)id * DD + i * 8;
    float4v v0 = *(const float4v*)s;
    float4v v1 = *(const float4v*)(s + 4);
    bf16x8 o;
    o[0] = f2bf(v0[0]); o[1] = f2bf(v0[1]); o[2] = f2bf(v0[2]); o[3] = f2bf(v0[3]);
    o[4] = f2bf(v1[0]); o[5] = f2bf(v1[1]); o[6] = f2bf(v1[2]); o[7] = f2bf(v1[3]);
    *(bf16x8*)(out + (size_t)r * DD + i * 8) = o;
  }
}

// ---------------- standalone bf16 GEMM (prologue only) ----------------
// EPI 0: fp32 store + bias (xg).  EPI 1: relu -> bf16 (fe).
template <int EPI>
__global__ __launch_bounds__(256) void k_gemm(const short* __restrict__ A,
                                              const short* __restrict__ BT,
                                              const float* __restrict__ bias,
                                              float* __restrict__ Cf,
                                              short* __restrict__ Cb,
                                              int N, int K, int ldc) {
  __shared__ short lA[128 * 32];
  __shared__ short lB[128 * 32];
  const int tid = threadIdx.x, wid = tid >> 6, lane = tid & 63;
  const int m0 = blockIdx.y * 128, n0 = blockIdx.x * 128;
  const int wr = wid >> 1, wc = wid & 1;
  f32x4 acc[4][4] = {};
  for (int kt = 0; kt < K / 32; ++kt) {
    const int kb = kt * 32;
#pragma unroll
    for (int rr = 0; rr < 2; ++rr) {
      int s = rr * 256 + tid;
      gload16(A + (size_t)(m0 + (s >> 2)) * K + kb + (s & 3) * 8, (char*)lA + s * 16);
      gload16(BT + (size_t)(n0 + (s >> 2)) * K + kb + (s & 3) * 8, (char*)lB + s * 16);
    }
    __syncthreads();
    bf16x8 af[4], bfr[4];
#pragma unroll
    for (int i = 0; i < 4; ++i)
      af[i] = *(const bf16x8*)(lA + (wr * 64 + i * 16 + (lane & 15)) * 32 + (lane >> 4) * 8);
#pragma unroll
    for (int j = 0; j < 4; ++j)
      bfr[j] = *(const bf16x8*)(lB + (wc * 64 + j * 16 + (lane & 15)) * 32 + (lane >> 4) * 8);
#pragma unroll
    for (int i = 0; i < 4; ++i)
#pragma unroll
      for (int j = 0; j < 4; ++j)
        acc[i][j] = __builtin_amdgcn_mfma_f32_16x16x32_bf16(af[i], bfr[j], acc[i][j], 0, 0, 0);
    __syncthreads();
  }
  const int hi = lane >> 4, ccol = lane & 15;
#pragma unroll
  for (int i = 0; i < 4; ++i) {
    int row = m0 + wr * 64 + i * 16 + hi * 4;
#pragma unroll
    for (int j = 0; j < 4; ++j) {
      int col = n0 + wc * 64 + j * 16 + ccol;
      if (col >= N) continue;
      float bv = bias ? bias[col] : 0.f;
#pragma unroll
      for (int rg = 0; rg < 4; ++rg) {
        int r = row + rg;
        float v = acc[i][j][rg] + bv;
        if (EPI == 0) Cf[(size_t)r * ldc + col] = v;
        else          Cb[(size_t)r * ldc + col] = f2bf(v < 0.f ? 0.f : v);
      }
    }
  }
}

// ------- fence-free grid barrier (R7): flag-store arrive + 25-lane poll -------
__device__ __forceinline__ void bar_sync(int* flags, int ep, int tid) {
  asm volatile("s_waitcnt vmcnt(0)" ::: "memory");   // per-wave store drain
  __syncthreads();
  if (tid == 0)
    __hip_atomic_store(&flags[blockIdx.x * 32], ep, __ATOMIC_RELAXED, __HIP_MEMORY_SCOPE_AGENT);
  if (tid < 64) {
    bool ok;
    do {
      int v = ep;
      if (tid < NBLK)
        v = __hip_atomic_load(&flags[tid * 32], __ATOMIC_RELAXED, __HIP_MEMORY_SCOPE_AGENT);
      ok = __all(v - ep >= 0);
      if (!ok) __builtin_amdgcn_s_sleep(1);
    } while (!ok);
  }
  __syncthreads();
}

// ---------------- fused: persistent GRU scan (blocks 0..24) + helper GEMM ----------------
// Workers: exact R11/R7 structure. Helpers (blocks >= 25): ticketed 128x128 GEMM,
// K=160 staging. HEPI 0: row-major tickets, fp32+bias (xg). HEPI 2 (logits):
// mb-GROUPED tickets (groups {10,8,4,2}, nb-major inside) so WoT panels are re-used
// within an IC-resident window; exp(v+bias) row-permuted NT-store + row partials.
template <int HEPI>
__global__ __launch_bounds__(512, 1) void k_fused(
    const float* __restrict__ xg, const short* __restrict__ UT,
    const float* __restrict__ br, float* __restrict__ hF,
    const short* __restrict__ hInit, short* __restrict__ hSeq,
    float* __restrict__ Spart, int* __restrict__ flags, int ep0,
    const short* __restrict__ gA, const short* __restrict__ gBT,
    const float* __restrict__ gbias, float* __restrict__ gCf,
    float* __restrict__ gPp, int gN, int gldc, int gNT, int gNtiles,
    int* __restrict__ tcnt, int pollBase) {
  __shared__ __align__(16) char smem[159744];
  const int tid = threadIdx.x, wid = tid >> 6, lane = tid & 63;
  const int hi = lane >> 4, ccol = lane & 15;

  if (blockIdx.x < NBLK) {
    // ================= WORKER: R11 scan, verbatim =================
    short* uT    = (short*)smem;               // [96][808]
    float* sSum  = (float*)(smem + 155136);    // [128]
    short* hTile = (short*)(smem + 155648);    // [64][32]
    const int bid = blockIdx.x, c0 = bid * 32;
    const int rt = wid & 3, ch = wid >> 2;
    for (int idx = tid; idx < 96 * 100; idx += 512) {
      int rr = idx / 100, chk = idx % 100;
      int grow = (rr >> 5) * HH + c0 + (rr & 31);
      *(bf16x8*)(uT + rr * 808 + chk * 8) = *(const bf16x8*)(UT + (size_t)grow * HH + chk * 8);
    }
    const int crow = rt * 16 + hi * 4;
    const int gcol = c0 + ch * 16 + ccol;
    const int arow = rt * 16 + ccol;
    const short* uz = uT + (0 * 32 + ch * 16 + ccol) * 808;
    const short* ur = uT + (1 * 32 + ch * 16 + ccol) * 808;
    const short* uh = uT + (2 * 32 + ch * 16 + ccol) * 808;
    f32x4 hfr;
#pragma unroll
    for (int rg = 0; rg < 4; ++rg) hfr[rg] = hF[(crow + rg) * HH + gcol];
    const float brz = br[gcol], brr = br[HH + gcol], brh = br[2 * HH + gcol];
    int ep = ep0;
    float xzv[4], xrv[4], xhv[4];
#pragma unroll
    for (int rg = 0; rg < 4; ++rg) {
      const float* xrow = xg + ((size_t)(crow + rg)) * N3H;
      xzv[rg] = xrow[gcol];
      xrv[rg] = xrow[HH + gcol];
      xhv[rg] = xrow[2 * HH + gcol];
    }
    __syncthreads();

#pragma unroll 1
    for (int t = 0; t < TT; ++t) {
      const short* hPrev = (t == 0) ? hInit : hSeq + (size_t)(t - 1) * BB * HH;
      bf16x8 areg[25];
#pragma unroll
      for (int kt = 0; kt < 25; ++kt)
        areg[kt] = *(const bf16x8*)(hPrev + arow * HH + kt * 32 + hi * 8);
      f32x4 az = {}, ar = {}, ah = {};
#pragma unroll
      for (int kt = 0; kt < 25; ++kt) {
        const int o = kt * 32 + hi * 8;
        az = __builtin_amdgcn_mfma_f32_16x16x32_bf16(areg[kt], *(const bf16x8*)(uz + o), az, 0, 0, 0);
        ar = __builtin_amdgcn_mfma_f32_16x16x32_bf16(areg[kt], *(const bf16x8*)(ur + o), ar, 0, 0, 0);
        ah = __builtin_amdgcn_mfma_f32_16x16x32_bf16(areg[kt], *(const bf16x8*)(uh + o), ah, 0, 0, 0);
      }
      float ez[4], er[4], rh[4];
      float* sb = Spart + (size_t)t * 50 * 128;
#pragma unroll
      for (int rg = 0; rg < 4; ++rg) {
        ez[rg] = __expf(xzv[rg] + az[rg] + brz);
        er[rg] = __expf(xrv[rg] + ar[rg] + brr);
        rh[rg] = ah[rg] + brh;
        float s1 = ez[rg], s2 = er[rg];
#pragma unroll
        for (int mm = 1; mm < 16; mm <<= 1) {
          s1 += __shfl_xor(s1, mm);
          s2 += __shfl_xor(s2, mm);
        }
        if (ccol == 0) {
          const int slot = bid * 2 + ch;
          __hip_atomic_store(&sb[slot * 128 + crow + rg], s1, __ATOMIC_RELAXED, __HIP_MEMORY_SCOPE_AGENT);
          __hip_atomic_store(&sb[slot * 128 + 64 + crow + rg], s2, __ATOMIC_RELAXED, __HIP_MEMORY_SCOPE_AGENT);
        }
      }
      bar_sync(flags, ++ep, tid);
      if (tid < 128) {
        float s = 0.f;
#pragma unroll
        for (int sl = 0; sl < 2 * NBLK; ++sl)
          s += __hip_atomic_load(&sb[sl * 128 + tid], __ATOMIC_RELAXED, __HIP_MEMORY_SCOPE_AGENT);
        sSum[tid] = s;
      }
      __syncthreads();
#pragma unroll
      for (int rg = 0; rg < 4; ++rg) {
        int r = crow + rg;
        float z = ez[rg] / sSum[r];
        float rr2 = er[rg] / sSum[64 + r];
        float hh = tanhf(xhv[rg] + rr2 * rh[rg]);
        float hn = z * hfr[rg] + (1.f - z) * hh;
        hfr[rg] = hn;
        hTile[r * 32 + ch * 16 + ccol] = f2bf(hn);
      }
      __syncthreads();
      short* hCur = hSeq + (size_t)t * BB * HH;
      if (tid < 256) {
        int row = tid >> 2, seg = tid & 3;
        store16_cc(hCur + row * HH + c0 + seg * 8, *(const bf16x8*)(hTile + row * 32 + seg * 8));
      }
      if (t + 1 < TT) {
#pragma unroll
        for (int rg = 0; rg < 4; ++rg) {
          const float* xrow = xg + ((size_t)(t + 1) * BB + crow + rg) * N3H;
          xzv[rg] = xrow[gcol];
          xrv[rg] = xrow[HH + gcol];
          xhv[rg] = xrow[2 * HH + gcol];
        }
      }
      bar_sync(flags, ++ep, tid);
    }
#pragma unroll
    for (int rg = 0; rg < 4; ++rg) hF[(crow + rg) * HH + gcol] = hfr[rg];
    return;
  }

  // ========= HELPER: ticketed 128x128 GEMM, K=160 staging (5 windows/tile) =========
  short* lA = (short*)smem;                 // [128][160] bf16 = 40960 B
  short* lB = (short*)(smem + 40960);       // [128][160]
  int*   tk = (int*)(smem + 81920);
  const int wr = wid >> 1, wc = wid & 1;
  for (;;) {
    if (tid == 0)
      tk[0] = __hip_atomic_fetch_add(tcnt, 1, __ATOMIC_RELAXED, __HIP_MEMORY_SCOPE_AGENT);
    __syncthreads();
    const int t0 = tk[0];
    if (t0 >= gNtiles) break;          // uniform across block
    int mb, nb;
    if (HEPI == 2) {
      // mb-grouped, nb-major inside group: groups {10,8,4,2} rows, decreasing so the
      // post-scan tail is short. WoT panel re-used across group rows -> IC-resident.
      if (t0 < 2500)      { int r2 = t0;        nb = r2 / 10; mb = 0  + r2 % 10; }
      else if (t0 < 4500) { int r2 = t0 - 2500; nb = r2 / 8;  mb = 10 + r2 % 8;  }
      else if (t0 < 5500) { int r2 = t0 - 4500; nb = r2 / 4;  mb = 18 + r2 % 4;  }
      else                { int r2 = t0 - 5500; nb = r2 / 2;  mb = 22 + r2 % 2;  }
    } else {
      mb = t0 / gNT; nb = t0 % gNT;
    }
    const int m0 = mb * 128, n0 = nb * 128;
    // poll: rows of tile mb are final once scan step 2*mb+1 is published
    {
      int tmax = 2 * mb + 1; if (tmax > TT - 1) tmax = TT - 1;
      const int ft = pollBase + 2 * tmax + 2;
      bool ok;
      do {
        int v = ft;
        if (lane < NBLK)
          v = __hip_atomic_load(&flags[lane * 32], __ATOMIC_RELAXED, __HIP_MEMORY_SCOPE_AGENT);
        ok = __all(v - ft >= 0);
        if (!ok) __builtin_amdgcn_s_sleep(2);
      } while (!ok);
      asm volatile("" ::: "memory");
    }
    f32x4 acc[2][4] = {};
#pragma unroll 1
    for (int kt = 0; kt < 5; ++kt) {
      const int kb = kt * 160;
#pragma unroll
      for (int i = 0; i < 5; ++i) {
        int c = tid + 512 * i;          // 16B chunk id, 0..2559 (row-major, 20/row)
        int row = c / 20, seg = c % 20;
        gload16(gA + (size_t)(m0 + row) * 800 + kb + seg * 8, (char*)lA + c * 16);
        gload16(gBT + (size_t)(n0 + row) * 800 + kb + seg * 8, (char*)lB + c * 16);
      }
      __syncthreads();
#pragma unroll
      for (int kk = 0; kk < 5; ++kk) {
        bf16x8 af[2], bf[4];
#pragma unroll
        for (int i = 0; i < 2; ++i)
          af[i] = *(const bf16x8*)(lA + (wr * 32 + i * 16 + (lane & 15)) * 160 + kk * 32 + hi * 8);
#pragma unroll
        for (int j = 0; j < 4; ++j)
          bf[j] = *(const bf16x8*)(lB + (wc * 64 + j * 16 + (lane & 15)) * 160 + kk * 32 + hi * 8);
#pragma unroll
        for (int i = 0; i < 2; ++i)
#pragma unroll
          for (int j = 0; j < 4; ++j)
            acc[i][j] = __builtin_amdgcn_mfma_f32_16x16x32_bf16(af[i], bf[j], acc[i][j], 0, 0, 0);
      }
      __syncthreads();
    }
    if (HEPI == 2) {
#pragma unroll
      for (int i = 0; i < 2; ++i) {
        int row = m0 + wr * 32 + i * 16 + hi * 4;
#pragma unroll
        for (int rg = 0; rg < 4; ++rg) {
          int r = row + rg;
          int orow = (r & 63) * TT + (r >> 6);   // (t,b) -> (b,t)
          float part = 0.f;
#pragma unroll
          for (int j = 0; j < 4; ++j) {
            int col = n0 + wc * 64 + j * 16 + ccol;
            float v = __expf(acc[i][j][rg] + gbias[col]);
            part += v;
            __builtin_nontemporal_store(v, &gCf[(size_t)orow * gldc + col]);  // NT: keep Wout IC-resident
          }
#pragma unroll
          for (int mm = 1; mm < 16; mm <<= 1) part += __shfl_xor(part, mm);
          if (ccol == 0) __builtin_nontemporal_store(part, &gPp[(size_t)orow * 512 + nb * 2 + wc]);
        }
      }
    } else {
#pragma unroll
      for (int i = 0; i < 2; ++i) {
        int row = m0 + wr * 32 + i * 16 + hi * 4;
#pragma unroll
        for (int j = 0; j < 4; ++j) {
          int col = n0 + wc * 64 + j * 16 + ccol;
          if (col >= gN) continue;
          float bv = gbias[col];
#pragma unroll
          for (int rg = 0; rg < 4; ++rg)
            gCf[(size_t)(row + rg) * gldc + col] = acc[i][j][rg] + bv;
        }
      }
    }
  }
}

// -------- normalize pass: sum 500 per-row partials, scale row (exp already stored) --------
__global__ __launch_bounds__(256) void k_softmax(float* __restrict__ out,
                                                 const float* __restrict__ Pp) {
  float* row = out + (size_t)blockIdx.x * VV;
  const float* pp = Pp + (size_t)blockIdx.x * 512;
  const int tid = threadIdx.x;
  __shared__ float red[4];
  float sum = 0.f;
  for (int i = tid; i < 500; i += 256) sum += pp[i];
#pragma unroll
  for (int s = 32; s >= 1; s >>= 1) sum += __shfl_xor(sum, s);
  if ((tid & 63) == 0) red[tid >> 6] = sum;
  __syncthreads();
  float inv = 1.f / (red[0] + red[1] + red[2] + red[3]);
  for (int i = tid * 4; i < VV; i += 1024) {
    float4v v = *(const float4v*)(row + i);
    v[0] *= inv; v[1] *= inv; v[2] *= inv; v[3] *= inv;
    *(float4v*)(row + i) = v;
  }
}

extern "C" void kernel_launch(void* const* d_in, const int* in_sizes, int n_in,
                              void* d_out, int out_size, void* d_ws, size_t ws_size,
                              hipStream_t stream) {
  (void)in_sizes; (void)n_in; (void)out_size; (void)ws_size;
  const int*   enc  = (const int*)d_in[0];
  const int*   dec  = (const int*)d_in[1];
  const float* embF = (const float*)d_in[2];
  const float* Wd1  = (const float*)d_in[3];
  const float* bd1  = (const float*)d_in[4];
  const float* Wf1  = (const float*)d_in[5];
  const float* Uf1  = (const float*)d_in[6];
  const float* bf1  = (const float*)d_in[7];
  const float* Wf2  = (const float*)d_in[8];
  const float* Uf2  = (const float*)d_in[9];
  const float* bf2  = (const float*)d_in[10];
  const float* embE = (const float*)d_in[11];
  const float* We1  = (const float*)d_in[12];
  const float* Ue1  = (const float*)d_in[13];
  const float* be1  = (const float*)d_in[14];
  const float* We2  = (const float*)d_in[15];
  const float* Ue2  = (const float*)d_in[16];
  const float* be2  = (const float*)d_in[17];
  const float* Wout = (const float*)d_in[18];
  const float* bout = (const float*)d_in[19];

  char* p = (char*)d_ws;
  auto alloc = [&](size_t bytes) { char* r = p; p += (bytes + 255) & ~(size_t)255; return r; };
  short* WdT = (short*)alloc((size_t)896 * 800 * 2);
  short* WTb[4]; short* UTb[4];
  for (int i = 0; i < 4; ++i) {
    WTb[i] = (short*)alloc((size_t)2432 * 800 * 2);
    UTb[i] = (short*)alloc((size_t)2400 * 800 * 2);
  }
  short* WoT = (short*)alloc((size_t)VV * 800 * 2);
  short* feA = (short*)alloc((size_t)MR * DD * 2);
  short* fe  = (short*)alloc((size_t)MR * DD * 2);
  short* ee  = (short*)alloc((size_t)MR * DD * 2);
  short* g1  = (short*)alloc((size_t)MR * HH * 2);
  short* g2s = (short*)alloc((size_t)MR * HH * 2);   // layer-1 hSeq scratch
  short* e1  = (short*)alloc((size_t)MR * HH * 2);
  short* e2  = (short*)alloc((size_t)MR * HH * 2);
  float* xgA = (float*)alloc((size_t)MR * N3H * 4);
  float* xgB = (float*)alloc((size_t)MR * N3H * 4);
  float* Ppart = (float*)alloc((size_t)MR * 512 * 4);
  float* Spart = (float*)alloc((size_t)TT * 50 * 128 * 4);
  // --- zeroed-at-launch region: hF .. tcnt ---
  float* hF   = (float*)alloc((size_t)BB * HH * 4);
  short* hIn0 = (short*)alloc((size_t)BB * HH * 2);
  int* flags  = (int*)alloc((size_t)NBLK * 32 * 4);
  int* tcnt   = (int*)alloc((size_t)16 * 4);

  size_t tail = (char*)(tcnt + 16) - (char*)hF;
  hipMemsetAsync(hF, 0, tail, stream);

  dim3 tb(32, 8);
  k_cast_transpose<<<dim3(25, 25), tb, 0, stream>>>(Wd1, WdT, 800, 800);
  const float* Ws[4] = {Wf1, Wf2, We1, We2};
  const float* Us[4] = {Uf1, Uf2, Ue1, Ue2};
  for (int i = 0; i < 4; ++i) {
    k_cast_transpose<<<dim3(75, 25), tb, 0, stream>>>(Ws[i], WTb[i], 800, 2400);
    k_cast_transpose<<<dim3(75, 25), tb, 0, stream>>>(Us[i], UTb[i], 800, 2400);
  }
  k_cast_transpose<<<dim3(1000, 25), tb, 0, stream>>>(Wout, WoT, 800, VV);
  k_gather<<<MR, 128, 0, stream>>>(enc, embF, feA);
  k_gather<<<MR, 128, 0, stream>>>(dec, embE, ee);
  // fe = relu(feA @ Wd1 + bd1) -> bf16 ; then xg(layer0) = fe @ Wf1 + bf1[0] -> xgA
  k_gemm<1><<<dim3(7, 24), 256, 0, stream>>>(feA, WdT, bd1, nullptr, fe, 800, 800, 800);
  k_gemm<0><<<dim3(19, 24), 256, 0, stream>>>(fe, WTb[0], bf1, xgA, nullptr, N3H, 800, N3H);

  const float* bs[4] = {bf1, bf2, be1, be2};
  short* hSeqL[4] = {g1, g2s, e1, e2};
  float* xgR[4] = {xgA, xgB, xgA, xgB};      // scan l reads
  // helper during scan l computes layer l+1's xg (or logits at l=3)
  const short* hA[4]   = {g1, ee, e1, e2};
  const short* hBT[4]  = {WTb[1], WTb[2], WTb[3], WoT};
  const float* hBias[4]= {bs[1], bs[2], bs[3], bout};
  float* hOut[4] = {xgB, xgA, xgB, (float*)d_out};
  int   hPoll[4] = {0 * 96, -1000000, 2 * 96, 3 * 96};   // l=1 input (ee) needs no poll

  for (int l = 0; l < 4; ++l) {
    const short* hInit = (l == 0) ? hIn0 : hSeqL[l - 1] + (size_t)(TT - 1) * BB * HH;
    if (l < 3) {
      k_fused<0><<<256, 512, 0, stream>>>(xgR[l], UTb[l], bs[l] + N3H, hF, hInit, hSeqL[l],
                                          Spart, flags, l * 2 * TT,
                                          hA[l], hBT[l], hBias[l], hOut[l], nullptr,
                                          N3H, N3H, 19, 24 * 19, &tcnt[l], hPoll[l]);
    } else {
      k_fused<2><<<256, 512, 0, stream>>>(xgR[l], UTb[l], bs[l] + N3H, hF, hInit, hSeqL[l],
                                          Spart, flags, l * 2 * TT,
                                          hA[l], hBT[l], hBias[l], hOut[l], Ppart,
                                          VV, VV, 250, 24 * 250, &tcnt[l], hPoll[l]);
    }
  }
  k_softmax<<<MR, 256, 0, stream>>>((float*)d_out, Ppart);
}

// Round 16
// 2207.972 us; speedup vs baseline: 1.2254x; 1.0288x over previous
//
#include <hip/hip_runtime.h>

#define DD 800
#define HH 800
#define BB 64
#define TT 48
#define N3H 2400
#define VV 32000
#define MR (TT*BB)   // 3072 rows, time-major (t*BB + b)
#define NBLK 25      // scan workers: 25 x 32 H-columns; blocks >= NBLK are GEMM helpers

typedef __attribute__((ext_vector_type(8))) short bf16x8;
typedef __attribute__((ext_vector_type(4))) short short4v;
typedef __attribute__((ext_vector_type(4))) float f32x4;
typedef __attribute__((ext_vector_type(4))) float float4v;
typedef __attribute__((address_space(1))) const unsigned int as1_uint;
typedef __attribute__((address_space(3))) unsigned int as3_uint;

__device__ __forceinline__ short f2bf(float f) {
  unsigned int u = __builtin_bit_cast(unsigned int, f);
  u = (u + 0x7fffu + ((u >> 16) & 1u)) >> 16;
  return (short)(unsigned short)u;
}
__device__ __forceinline__ float bf2f(short s) {
  return __builtin_bit_cast(float, (unsigned int)(unsigned short)s << 16);
}

__device__ __forceinline__ void gload16(const void* g, void* l) {
  __builtin_amdgcn_global_load_lds((as1_uint*)g, (as3_uint*)l, 16, 0, 0);
}

// device-coherent 16B store: write-through to IC (visible chip-wide after vmcnt drain).
__device__ __forceinline__ void store16_cc(short* p, bf16x8 v) {
  asm volatile("global_store_dwordx4 %0, %1, off sc0 sc1" :: "v"(p), "v"(v));
}

// ---------------- transpose + cast fp32 [K][N] -> bf16 [N][K] ----------------
__device__ __forceinline__ void cast_transpose_body(const float* __restrict__ src,
                                                    short* __restrict__ dst,
                                                    int K, int N) {
  __shared__ float tile[32][33];
  int n0 = blockIdx.x * 32, k0 = blockIdx.y * 32;
  int tx = threadIdx.x, ty = threadIdx.y;   // (32,8)
#pragma unroll
  for (int i = 0; i < 4; ++i) {
    int k = k0 + ty + i * 8, n = n0 + tx;
    if (k < K && n < N) tile[ty + i * 8][tx] = src[(size_t)k * N + n];
  }
  __syncthreads();
#pragma unroll
  for (int i = 0; i < 4; ++i) {
    int n = n0 + ty + i * 8, k = k0 + tx;
    if (n < N && k < K) dst[(size_t)n * K + k] = f2bf(tile[tx][ty + i * 8]);
  }
}

__global__ void k_cast_transpose(const float* __restrict__ src, short* __restrict__ dst,
                                 int K, int N) {
  cast_transpose_body(src, dst, K, N);
}

struct CastBatch { const float* src[8]; short* dst[8]; };
__global__ void k_cast8(CastBatch cb) {   // 8x [800][2400] -> [2400][800]
  cast_transpose_body(cb.src[blockIdx.z], cb.dst[blockIdx.z], 800, 2400);
}

// ---------------- gather embedding rows -> bf16, time-major ----------------
__global__ void k_gather(const int* __restrict__ ids, const float* __restrict__ emb,
                         short* __restrict__ out) {
  int r = blockIdx.x;            // r = t*BB + b
  int t = r >> 6, b = r & 63;
  int id = ids[b * TT + t];
  int i = threadIdx.x;
  if (i < 100) {
    const float* s = emb + (size_t)id * DD + i * 8;
    float4v v0 = *(const float4v*)s;
    float4v v1 = *(const float4v*)(s + 4);
    bf16x8 o;
    o[0] = f2bf(v0[0]); o[1] = f2bf(v0[1]); o[2] = f2bf(v0[2]); o[3] = f2bf(v0[3]);
    o[4] = f2bf(v1[0]); o[5] = f2bf(v1[1]); o[6] = f2bf(v1[2]); o[7] = f2bf(v1[3]);
    *(bf16x8*)(out + (size_t)r * DD + i * 8) = o;
  }
}

// ---------------- standalone bf16 GEMM (prologue only) ----------------
// EPI 0: fp32 store + bias (xg).  EPI 1: relu -> bf16 (fe).
template <int EPI>
__global__ __launch_bounds__(256) void k_gemm(const short* __restrict__ A,
                                              const short* __restrict__ BT,
                                              const float* __restrict__ bias,
                                              float* __restrict__ Cf,
                                              short* __restrict__ Cb,
                                              int N, int K, int ldc) {
  __shared__ short lA[128 * 32];
  __shared__ short lB[128 * 32];
  const int tid = threadIdx.x, wid = tid >> 6, lane = tid & 63;
  const int m0 = blockIdx.y * 128, n0 = blockIdx.x * 128;
  const int wr = wid >> 1, wc = wid & 1;
  f32x4 acc[4][4] = {};
  for (int kt = 0; kt < K / 32; ++kt) {
    const int kb = kt * 32;
#pragma unroll
    for (int rr = 0; rr < 2; ++rr) {
      int s = rr * 256 + tid;
      gload16(A + (size_t)(m0 + (s >> 2)) * K + kb + (s & 3) * 8, (char*)lA + s * 16);
      gload16(BT + (size_t)(n0 + (s >> 2)) * K + kb + (s & 3) * 8, (char*)lB + s * 16);
    }
    __syncthreads();
    bf16x8 af[4], bfr[4];
#pragma unroll
    for (int i = 0; i < 4; ++i)
      af[i] = *(const bf16x8*)(lA + (wr * 64 + i * 16 + (lane & 15)) * 32 + (lane >> 4) * 8);
#pragma unroll
    for (int j = 0; j < 4; ++j)
      bfr[j] = *(const bf16x8*)(lB + (wc * 64 + j * 16 + (lane & 15)) * 32 + (lane >> 4) * 8);
#pragma unroll
    for (int i = 0; i < 4; ++i)
#pragma unroll
      for (int j = 0; j < 4; ++j)
        acc[i][j] = __builtin_amdgcn_mfma_f32_16x16x32_bf16(af[i], bfr[j], acc[i][j], 0, 0, 0);
    __syncthreads();
  }
  const int hi = lane >> 4, ccol = lane & 15;
#pragma unroll
  for (int i = 0; i < 4; ++i) {
    int row = m0 + wr * 64 + i * 16 + hi * 4;
#pragma unroll
    for (int j = 0; j < 4; ++j) {
      int col = n0 + wc * 64 + j * 16 + ccol;
      if (col >= N) continue;
      float bv = bias ? bias[col] : 0.f;
#pragma unroll
      for (int rg = 0; rg < 4; ++rg) {
        int r = row + rg;
        float v = acc[i][j][rg] + bv;
        if (EPI == 0) Cf[(size_t)r * ldc + col] = v;
        else          Cb[(size_t)r * ldc + col] = f2bf(v < 0.f ? 0.f : v);
      }
    }
  }
}

// ------- fence-free grid barrier (R7): flag-store arrive + 25-lane poll -------
__device__ __forceinline__ void bar_sync(int* flags, int ep, int tid) {
  asm volatile("s_waitcnt vmcnt(0)" ::: "memory");   // per-wave store drain
  __syncthreads();
  if (tid == 0)
    __hip_atomic_store(&flags[blockIdx.x * 32], ep, __ATOMIC_RELAXED, __HIP_MEMORY_SCOPE_AGENT);
  if (tid < 64) {
    bool ok;
    do {
      int v = ep;
      if (tid < NBLK)
        v = __hip_atomic_load(&flags[tid * 32], __ATOMIC_RELAXED, __HIP_MEMORY_SCOPE_AGENT);
      ok = __all(v - ep >= 0);
      if (!ok) __builtin_amdgcn_s_sleep(1);
    } while (!ok);
  }
  __syncthreads();
}

// ---------------- fused: persistent GRU scan (blocks 0..24) + helper GEMM ----------------
// Workers: exact R11/R7 structure. Helpers (blocks >= 25): ticketed 128x128 GEMM,
// K=160 staging. HEPI 0: row-major tickets, fp32+bias (xg). HEPI 2 (logits):
// mb-GROUPED tickets; exp(v+bias) -> BF16 staged into row's own fp32 slot in d_out
// (halves the write stream; WoT stays IC-resident) + per-wave row partials.
template <int HEPI>
__global__ __launch_bounds__(512, 1) void k_fused(
    const float* __restrict__ xg, const short* __restrict__ UT,
    const float* __restrict__ br, float* __restrict__ hF,
    const short* __restrict__ hInit, short* __restrict__ hSeq,
    float* __restrict__ Spart, int* __restrict__ flags, int ep0,
    const short* __restrict__ gA, const short* __restrict__ gBT,
    const float* __restrict__ gbias, float* __restrict__ gCf,
    float* __restrict__ gPp, int gN, int gldc, int gNT, int gNtiles,
    int* __restrict__ tcnt, int pollBase) {
  __shared__ __align__(16) char smem[159744];
  const int tid = threadIdx.x, wid = tid >> 6, lane = tid & 63;
  const int hi = lane >> 4, ccol = lane & 15;

  if (blockIdx.x < NBLK) {
    // ================= WORKER: R11 scan, verbatim =================
    short* uT    = (short*)smem;               // [96][808]
    float* sSum  = (float*)(smem + 155136);    // [128]
    short* hTile = (short*)(smem + 155648);    // [64][32]
    const int bid = blockIdx.x, c0 = bid * 32;
    const int rt = wid & 3, ch = wid >> 2;
    for (int idx = tid; idx < 96 * 100; idx += 512) {
      int rr = idx / 100, chk = idx % 100;
      int grow = (rr >> 5) * HH + c0 + (rr & 31);
      *(bf16x8*)(uT + rr * 808 + chk * 8) = *(const bf16x8*)(UT + (size_t)grow * HH + chk * 8);
    }
    const int crow = rt * 16 + hi * 4;
    const int gcol = c0 + ch * 16 + ccol;
    const int arow = rt * 16 + ccol;
    const short* uz = uT + (0 * 32 + ch * 16 + ccol) * 808;
    const short* ur = uT + (1 * 32 + ch * 16 + ccol) * 808;
    const short* uh = uT + (2 * 32 + ch * 16 + ccol) * 808;
    f32x4 hfr;
#pragma unroll
    for (int rg = 0; rg < 4; ++rg) hfr[rg] = hF[(crow + rg) * HH + gcol];
    const float brz = br[gcol], brr = br[HH + gcol], brh = br[2 * HH + gcol];
    int ep = ep0;
    float xzv[4], xrv[4], xhv[4];
#pragma unroll
    for (int rg = 0; rg < 4; ++rg) {
      const float* xrow = xg + ((size_t)(crow + rg)) * N3H;
      xzv[rg] = xrow[gcol];
      xrv[rg] = xrow[HH + gcol];
      xhv[rg] = xrow[2 * HH + gcol];
    }
    __syncthreads();

#pragma unroll 1
    for (int t = 0; t < TT; ++t) {
      const short* hPrev = (t == 0) ? hInit : hSeq + (size_t)(t - 1) * BB * HH;
      bf16x8 areg[25];
#pragma unroll
      for (int kt = 0; kt < 25; ++kt)
        areg[kt] = *(const bf16x8*)(hPrev + arow * HH + kt * 32 + hi * 8);
      f32x4 az = {}, ar = {}, ah = {};
#pragma unroll
      for (int kt = 0; kt < 25; ++kt) {
        const int o = kt * 32 + hi * 8;
        az = __builtin_amdgcn_mfma_f32_16x16x32_bf16(areg[kt], *(const bf16x8*)(uz + o), az, 0, 0, 0);
        ar = __builtin_amdgcn_mfma_f32_16x16x32_bf16(areg[kt], *(const bf16x8*)(ur + o), ar, 0, 0, 0);
        ah = __builtin_amdgcn_mfma_f32_16x16x32_bf16(areg[kt], *(const bf16x8*)(uh + o), ah, 0, 0, 0);
      }
      float ez[4], er[4], rh[4];
      float* sb = Spart + (size_t)t * 50 * 128;
#pragma unroll
      for (int rg = 0; rg < 4; ++rg) {
        ez[rg] = __expf(xzv[rg] + az[rg] + brz);
        er[rg] = __expf(xrv[rg] + ar[rg] + brr);
        rh[rg] = ah[rg] + brh;
        float s1 = ez[rg], s2 = er[rg];
#pragma unroll
        for (int mm = 1; mm < 16; mm <<= 1) {
          s1 += __shfl_xor(s1, mm);
          s2 += __shfl_xor(s2, mm);
        }
        if (ccol == 0) {
          const int slot = bid * 2 + ch;
          __hip_atomic_store(&sb[slot * 128 + crow + rg], s1, __ATOMIC_RELAXED, __HIP_MEMORY_SCOPE_AGENT);
          __hip_atomic_store(&sb[slot * 128 + 64 + crow + rg], s2, __ATOMIC_RELAXED, __HIP_MEMORY_SCOPE_AGENT);
        }
      }
      bar_sync(flags, ++ep, tid);
      if (tid < 128) {
        float s = 0.f;
#pragma unroll
        for (int sl = 0; sl < 2 * NBLK; ++sl)
          s += __hip_atomic_load(&sb[sl * 128 + tid], __ATOMIC_RELAXED, __HIP_MEMORY_SCOPE_AGENT);
        sSum[tid] = s;
      }
      __syncthreads();
#pragma unroll
      for (int rg = 0; rg < 4; ++rg) {
        int r = crow + rg;
        float z = ez[rg] / sSum[r];
        float rr2 = er[rg] / sSum[64 + r];
        float hh = tanhf(xhv[rg] + rr2 * rh[rg]);
        float hn = z * hfr[rg] + (1.f - z) * hh;
        hfr[rg] = hn;
        hTile[r * 32 + ch * 16 + ccol] = f2bf(hn);
      }
      __syncthreads();
      short* hCur = hSeq + (size_t)t * BB * HH;
      if (tid < 256) {
        int row = tid >> 2, seg = tid & 3;
        store16_cc(hCur + row * HH + c0 + seg * 8, *(const bf16x8*)(hTile + row * 32 + seg * 8));
      }
      if (t + 1 < TT) {
#pragma unroll
        for (int rg = 0; rg < 4; ++rg) {
          const float* xrow = xg + ((size_t)(t + 1) * BB + crow + rg) * N3H;
          xzv[rg] = xrow[gcol];
          xrv[rg] = xrow[HH + gcol];
          xhv[rg] = xrow[2 * HH + gcol];
        }
      }
      bar_sync(flags, ++ep, tid);
    }
#pragma unroll
    for (int rg = 0; rg < 4; ++rg) hF[(crow + rg) * HH + gcol] = hfr[rg];
    return;
  }

  // ========= HELPER: ticketed 128x128 GEMM, K=160 staging (5 windows/tile) =========
  short* lA = (short*)smem;                 // [128][160] bf16 = 40960 B
  short* lB = (short*)(smem + 40960);       // [128][160]
  int*   tk = (int*)(smem + 81920);
  const int wr = wid >> 1, wc = wid & 1;
  for (;;) {
    if (tid == 0)
      tk[0] = __hip_atomic_fetch_add(tcnt, 1, __ATOMIC_RELAXED, __HIP_MEMORY_SCOPE_AGENT);
    __syncthreads();
    const int t0 = tk[0];
    if (t0 >= gNtiles) break;          // uniform across block
    int mb, nb;
    if (HEPI == 2) {
      // mb-grouped, nb-major inside group: groups {10,8,4,2} rows (decreasing tail).
      if (t0 < 2500)      { int r2 = t0;        nb = r2 / 10; mb = 0  + r2 % 10; }
      else if (t0 < 4500) { int r2 = t0 - 2500; nb = r2 / 8;  mb = 10 + r2 % 8;  }
      else if (t0 < 5500) { int r2 = t0 - 4500; nb = r2 / 4;  mb = 18 + r2 % 4;  }
      else                { int r2 = t0 - 5500; nb = r2 / 2;  mb = 22 + r2 % 2;  }
    } else {
      mb = t0 / gNT; nb = t0 % gNT;
    }
    const int m0 = mb * 128, n0 = nb * 128;
    // poll: rows of tile mb are final once scan step 2*mb+1 is published
    {
      int tmax = 2 * mb + 1; if (tmax > TT - 1) tmax = TT - 1;
      const int ft = pollBase + 2 * tmax + 2;
      bool ok;
      do {
        int v = ft;
        if (lane < NBLK)
          v = __hip_atomic_load(&flags[lane * 32], __ATOMIC_RELAXED, __HIP_MEMORY_SCOPE_AGENT);
        ok = __all(v - ft >= 0);
        if (!ok) __builtin_amdgcn_s_sleep(2);
      } while (!ok);
      asm volatile("" ::: "memory");
    }
    f32x4 acc[2][4] = {};
#pragma unroll 1
    for (int kt = 0; kt < 5; ++kt) {
      const int kb = kt * 160;
#pragma unroll
      for (int i = 0; i < 5; ++i) {
        int c = tid + 512 * i;          // 16B chunk id, 0..2559 (row-major, 20/row)
        int row = c / 20, seg = c % 20;
        gload16(gA + (size_t)(m0 + row) * 800 + kb + seg * 8, (char*)lA + c * 16);
        gload16(gBT + (size_t)(n0 + row) * 800 + kb + seg * 8, (char*)lB + c * 16);
      }
      __syncthreads();
#pragma unroll
      for (int kk = 0; kk < 5; ++kk) {
        bf16x8 af[2], bf[4];
#pragma unroll
        for (int i = 0; i < 2; ++i)
          af[i] = *(const bf16x8*)(lA + (wr * 32 + i * 16 + (lane & 15)) * 160 + kk * 32 + hi * 8);
#pragma unroll
        for (int j = 0; j < 4; ++j)
          bf[j] = *(const bf16x8*)(lB + (wc * 64 + j * 16 + (lane & 15)) * 160 + kk * 32 + hi * 8);
#pragma unroll
        for (int i = 0; i < 2; ++i)
#pragma unroll
          for (int j = 0; j < 4; ++j)
            acc[i][j] = __builtin_amdgcn_mfma_f32_16x16x32_bf16(af[i], bf[j], acc[i][j], 0, 0, 0);
      }
      __syncthreads();
    }
    if (HEPI == 2) {
      short* eb = (short*)gCf;   // bf16 exp staged at row's own fp32 slot start
#pragma unroll
      for (int i = 0; i < 2; ++i) {
        int row = m0 + wr * 32 + i * 16 + hi * 4;
#pragma unroll
        for (int rg = 0; rg < 4; ++rg) {
          int r = row + rg;
          int orow = (r & 63) * TT + (r >> 6);   // (t,b) -> (b,t)
          float part = 0.f;
#pragma unroll
          for (int j = 0; j < 4; ++j) {
            int col = n0 + wc * 64 + j * 16 + ccol;
            float v = __expf(acc[i][j][rg] + gbias[col]);
            part += v;
            __builtin_nontemporal_store(f2bf(v), &eb[(size_t)orow * 2 * VV + col]);
          }
#pragma unroll
          for (int mm = 1; mm < 16; mm <<= 1) part += __shfl_xor(part, mm);
          if (ccol == 0) __builtin_nontemporal_store(part, &gPp[(size_t)orow * 512 + nb * 2 + wc]);
        }
      }
    } else {
#pragma unroll
      for (int i = 0; i < 2; ++i) {
        int row = m0 + wr * 32 + i * 16 + hi * 4;
#pragma unroll
        for (int j = 0; j < 4; ++j) {
          int col = n0 + wc * 64 + j * 16 + ccol;
          if (col >= gN) continue;
          float bv = gbias[col];
#pragma unroll
          for (int rg = 0; rg < 4; ++rg)
            gCf[(size_t)(row + rg) * gldc + col] = acc[i][j][rg] + bv;
        }
      }
    }
  }
}

// -------- normalize pass: sum 500 partials, expand bf16 exp (in-place) -> fp32/sum --------
// bf16 row r occupies shorts [2*r*VV, 2*r*VV+VV) = first half of row r's fp32 slot.
// Expand DESCENDING: fp32 write of chunk j only clobbers bf16 chunks >= 2j (done).
__global__ __launch_bounds__(256) void k_softmax(float* __restrict__ out,
                                                 const float* __restrict__ Pp) {
  const size_t base = (size_t)blockIdx.x * VV;
  float* row = out + base;
  const short* eb = (const short*)out + 2 * base;
  const float* pp = Pp + (size_t)blockIdx.x * 512;
  const int tid = threadIdx.x;
  __shared__ float red[4];
  float sum = 0.f;
  for (int i = tid; i < 500; i += 256) sum += pp[i];
#pragma unroll
  for (int s = 32; s >= 1; s >>= 1) sum += __shfl_xor(sum, s);
  if ((tid & 63) == 0) red[tid >> 6] = sum;
  __syncthreads();
  float inv = 1.f / (red[0] + red[1] + red[2] + red[3]);
#pragma unroll 1
  for (int j = 31; j >= 0; --j) {
    int i = j * 1024 + tid * 4;
    bool act = (i < VV);
    short4v v = {};
    if (act) v = *(const short4v*)(eb + i);
    __syncthreads();
    if (act) {
      float4v o;
      o[0] = bf2f(v[0]) * inv; o[1] = bf2f(v[1]) * inv;
      o[2] = bf2f(v[2]) * inv; o[3] = bf2f(v[3]) * inv;
      *(float4v*)(row + i) = o;
    }
  }
}

extern "C" void kernel_launch(void* const* d_in, const int* in_sizes, int n_in,
                              void* d_out, int out_size, void* d_ws, size_t ws_size,
                              hipStream_t stream) {
  (void)in_sizes; (void)n_in; (void)out_size; (void)ws_size;
  const int*   enc  = (const int*)d_in[0];
  const int*   dec  = (const int*)d_in[1];
  const float* embF = (const float*)d_in[2];
  const float* Wd1  = (const float*)d_in[3];
  const float* bd1  = (const float*)d_in[4];
  const float* Wf1  = (const float*)d_in[5];
  const float* Uf1  = (const float*)d_in[6];
  const float* bf1  = (const float*)d_in[7];
  const float* Wf2  = (const float*)d_in[8];
  const float* Uf2  = (const float*)d_in[9];
  const float* bf2  = (const float*)d_in[10];
  const float* embE = (const float*)d_in[11];
  const float* We1  = (const float*)d_in[12];
  const float* Ue1  = (const float*)d_in[13];
  const float* be1  = (const float*)d_in[14];
  const float* We2  = (const float*)d_in[15];
  const float* Ue2  = (const float*)d_in[16];
  const float* be2  = (const float*)d_in[17];
  const float* Wout = (const float*)d_in[18];
  const float* bout = (const float*)d_in[19];

  char* p = (char*)d_ws;
  auto alloc = [&](size_t bytes) { char* r = p; p += (bytes + 255) & ~(size_t)255; return r; };
  short* WdT = (short*)alloc((size_t)896 * 800 * 2);
  short* WTb[4]; short* UTb[4];
  for (int i = 0; i < 4; ++i) {
    WTb[i] = (short*)alloc((size_t)2432 * 800 * 2);
    UTb[i] = (short*)alloc((size_t)2400 * 800 * 2);
  }
  short* WoT = (short*)alloc((size_t)VV * 800 * 2);
  short* feA = (short*)alloc((size_t)MR * DD * 2);
  short* fe  = (short*)alloc((size_t)MR * DD * 2);
  short* ee  = (short*)alloc((size_t)MR * DD * 2);
  short* g1  = (short*)alloc((size_t)MR * HH * 2);
  short* g2s = (short*)alloc((size_t)MR * HH * 2);   // layer-1 hSeq scratch
  short* e1  = (short*)alloc((size_t)MR * HH * 2);
  short* e2  = (short*)alloc((size_t)MR * HH * 2);
  float* xgA = (float*)alloc((size_t)MR * N3H * 4);
  float* xgB = (float*)alloc((size_t)MR * N3H * 4);
  float* Ppart = (float*)alloc((size_t)MR * 512 * 4);
  float* Spart = (float*)alloc((size_t)TT * 50 * 128 * 4);
  // --- zeroed-at-launch region: hF .. tcnt ---
  float* hF   = (float*)alloc((size_t)BB * HH * 4);
  short* hIn0 = (short*)alloc((size_t)BB * HH * 2);
  int* flags  = (int*)alloc((size_t)NBLK * 32 * 4);
  int* tcnt   = (int*)alloc((size_t)16 * 4);

  size_t tail = (char*)(tcnt + 16) - (char*)hF;
  hipMemsetAsync(hF, 0, tail, stream);

  dim3 tb(32, 8);
  k_cast_transpose<<<dim3(25, 25), tb, 0, stream>>>(Wd1, WdT, 800, 800);
  CastBatch cb;
  cb.src[0] = Wf1; cb.src[1] = Wf2; cb.src[2] = We1; cb.src[3] = We2;
  cb.src[4] = Uf1; cb.src[5] = Uf2; cb.src[6] = Ue1; cb.src[7] = Ue2;
  cb.dst[0] = WTb[0]; cb.dst[1] = WTb[1]; cb.dst[2] = WTb[2]; cb.dst[3] = WTb[3];
  cb.dst[4] = UTb[0]; cb.dst[5] = UTb[1]; cb.dst[6] = UTb[2]; cb.dst[7] = UTb[3];
  k_cast8<<<dim3(75, 25, 8), tb, 0, stream>>>(cb);
  k_cast_transpose<<<dim3(1000, 25), tb, 0, stream>>>(Wout, WoT, 800, VV);
  k_gather<<<MR, 128, 0, stream>>>(enc, embF, feA);
  k_gather<<<MR, 128, 0, stream>>>(dec, embE, ee);
  // fe = relu(feA @ Wd1 + bd1) -> bf16 ; then xg(layer0) = fe @ Wf1 + bf1[0] -> xgA
  k_gemm<1><<<dim3(7, 24), 256, 0, stream>>>(feA, WdT, bd1, nullptr, fe, 800, 800, 800);
  k_gemm<0><<<dim3(19, 24), 256, 0, stream>>>(fe, WTb[0], bf1, xgA, nullptr, N3H, 800, N3H);

  const float* bs[4] = {bf1, bf2, be1, be2};
  short* hSeqL[4] = {g1, g2s, e1, e2};
  float* xgR[4] = {xgA, xgB, xgA, xgB};      // scan l reads
  // helper during scan l computes layer l+1's xg (or logits at l=3)
  const short* hA[4]   = {g1, ee, e1, e2};
  const short* hBT[4]  = {WTb[1], WTb[2], WTb[3], WoT};
  const float* hBias[4]= {bs[1], bs[2], bs[3], bout};
  float* hOut[4] = {xgB, xgA, xgB, (float*)d_out};
  int   hPoll[4] = {0 * 96, -1000000, 2 * 96, 3 * 96};   // l=1 input (ee) needs no poll

  for (int l = 0; l < 4; ++l) {
    const short* hInit = (l == 0) ? hIn0 : hSeqL[l - 1] + (size_t)(TT - 1) * BB * HH;
    if (l < 3) {
      k_fused<0><<<256, 512, 0, stream>>>(xgR[l], UTb[l], bs[l] + N3H, hF, hInit, hSeqL[l],
                                          Spart, flags, l * 2 * TT,
                                          hA[l], hBT[l], hBias[l], hOut[l], nullptr,
                                          N3H, N3H, 19, 24 * 19, &tcnt[l], hPoll[l]);
    } else {
      k_fused<2><<<256, 512, 0, stream>>>(xgR[l], UTb[l], bs[l] + N3H, hF, hInit, hSeqL[l],
                                          Spart, flags, l * 2 * TT,
                                          hA[l], hBT[l], hBias[l], hOut[l], Ppart,
                                          VV, VV, 250, 24 * 250, &tcnt[l], hPoll[l]);
    }
  }
  k_softmax<<<MR, 256, 0, stream>>>((float*)d_out, Ppart);
}